// Round 1
// baseline (544.347 us; speedup 1.0000x reference)
//
#include <hip/hip_runtime.h>

using bf16x8 = __attribute__((ext_vector_type(8))) short;
using f32x4  = __attribute__((ext_vector_type(4))) float;

#define MFMA(a,b,c) __builtin_amdgcn_mfma_f32_16x16x32_bf16((a),(b),(c),0,0,0)

static constexpr int NB = 4, NC = 512, NN = 4096, ND = 64;

__device__ __forceinline__ short f2bf(float f) {
  union { float f; unsigned u; } v; v.f = f;
  unsigned r = v.u + 0x7FFFu + ((v.u >> 16) & 1u);
  return (short)(r >> 16);
}

// ---------------- kernel 1: cast weights to bf16 ----------------
__global__ void cast_w(const float* Wq, const float* Wk, const float* Wv,
                       short* Wqb, short* Wkb, short* Wvb) {
  int i = blockIdx.x * 256 + threadIdx.x;
  if (i < ND * NC) { Wqb[i] = f2bf(Wq[i]); Wkb[i] = f2bf(Wk[i]); }
  if (i < NC * NC) { Wvb[i] = f2bf(Wv[i]); }
}

// ---------------- kernel 2: x (B,C,N) f32 -> xT (B,N,C) bf16 ----------------
__global__ void transpose_x(const float* x, short* xT) {
  __shared__ short tile[32][34];
  int b  = blockIdx.z;
  int c0 = blockIdx.y * 32;
  int n0 = blockIdx.x * 32;
  const float* xb = x + (size_t)b * NC * NN;
  short* xTb = xT + (size_t)b * NN * NC;
  int tx = threadIdx.x, ty = threadIdx.y;
  for (int i = 0; i < 4; i++)
    tile[ty + i * 8][tx] = f2bf(xb[(size_t)(c0 + ty + i * 8) * NN + n0 + tx]);
  __syncthreads();
  for (int i = 0; i < 4; i++)
    xTb[(size_t)(n0 + ty + i * 8) * NC + c0 + tx] = tile[tx][ty + i * 8];
}

// ---------------- kernel 3: Q,K projections -> (B,N,64) bf16 ----------------
// Q[n][d] = sum_c xT[n][c] * Wq[d][c] + bq[d]
__global__ __launch_bounds__(256) void proj_qk(const short* xT, const short* Wqb, const short* Wkb,
                        const float* bq, const float* bk, short* Q, short* K) {
  int b = blockIdx.y;
  int wave = threadIdx.x >> 6, lane = threadIdx.x & 63;
  int lc = lane & 15, grp = lane >> 4;
  int n0 = blockIdx.x * 64 + wave * 16;
  const short* xTb = xT + ((size_t)b * NN + n0) * NC;
  f32x4 accq[4] = {}, acck[4] = {};
  for (int c0 = 0; c0 < NC; c0 += 32) {
    bf16x8 a = *(const bf16x8*)(xTb + (size_t)lc * NC + c0 + grp * 8);
    for (int di = 0; di < 4; di++) {
      bf16x8 wq = *(const bf16x8*)(Wqb + (size_t)(di * 16 + lc) * NC + c0 + grp * 8);
      bf16x8 wk = *(const bf16x8*)(Wkb + (size_t)(di * 16 + lc) * NC + c0 + grp * 8);
      accq[di] = MFMA(a, wq, accq[di]);
      acck[di] = MFMA(a, wk, acck[di]);
    }
  }
  short* Qb = Q + (size_t)b * NN * ND;
  short* Kb = K + (size_t)b * NN * ND;
  for (int di = 0; di < 4; di++)
    for (int j = 0; j < 4; j++) {
      int n = n0 + grp * 4 + j;
      int d = di * 16 + lc;
      Qb[(size_t)n * ND + d] = f2bf(accq[di][j] + bq[d]);
      Kb[(size_t)n * ND + d] = f2bf(acck[di][j] + bk[d]);
    }
}

// ---------------- kernel 4: V projection -> (B,C,N) bf16 ----------------
// V[e][n] = sum_c Wv[e][c] * xT[n][c] + bv[e]
__global__ __launch_bounds__(256) void proj_v(const short* xT, const short* Wvb, const float* bv, short* V) {
  int b = blockIdx.z;
  int wave = threadIdx.x >> 6, lane = threadIdx.x & 63;
  int lc = lane & 15, grp = lane >> 4;
  int e0 = blockIdx.y * 64 + wave * 16;
  int n0 = blockIdx.x * 128;
  const short* xTb = xT + (size_t)b * NN * NC;
  f32x4 acc[8] = {};
  for (int c0 = 0; c0 < NC; c0 += 32) {
    bf16x8 a = *(const bf16x8*)(Wvb + (size_t)(e0 + lc) * NC + c0 + grp * 8);
    for (int ni = 0; ni < 8; ni++) {
      bf16x8 bfr = *(const bf16x8*)(xTb + (size_t)(n0 + ni * 16 + lc) * NC + c0 + grp * 8);
      acc[ni] = MFMA(a, bfr, acc[ni]);
    }
  }
  short* Vb = V + (size_t)b * NC * NN;
  for (int ni = 0; ni < 8; ni++)
    for (int j = 0; j < 4; j++) {
      int e = e0 + grp * 4 + j;
      int n = n0 + ni * 16 + lc;
      Vb[(size_t)e * NN + n] = f2bf(acc[ni][j] + bv[e]);
    }
}

// ---------------- kernel 5: softmax stats (row max, sumexp) ----------------
__global__ __launch_bounds__(64) void attn_stats(const short* Q, const short* K,
                                                 float* Mrow, float* Lrow) {
  int b = blockIdx.y;
  int m0 = blockIdx.x * 32;
  int lane = threadIdx.x;
  int lc = lane & 15, grp = lane >> 4;
  const short* Qb = Q + (size_t)b * NN * ND;
  const short* Kb = K + (size_t)b * NN * ND;
  bf16x8 qf[2][2];
  for (int mi = 0; mi < 2; mi++)
    for (int kk = 0; kk < 2; kk++)
      qf[mi][kk] = *(const bf16x8*)(Qb + (size_t)(m0 + mi * 16 + lc) * ND + kk * 32 + grp * 8);
  float rmax[2][4], rsum[2][4];
  for (int mi = 0; mi < 2; mi++)
    for (int j = 0; j < 4; j++) { rmax[mi][j] = -1e30f; rsum[mi][j] = 0.f; }
  for (int n0 = 0; n0 < NN; n0 += 32) {
    f32x4 s[2][2] = {};
    for (int ni = 0; ni < 2; ni++) {
      const short* kp = Kb + (size_t)(n0 + ni * 16 + lc) * ND + grp * 8;
      bf16x8 kf0 = *(const bf16x8*)(kp);
      bf16x8 kf1 = *(const bf16x8*)(kp + 32);
      for (int mi = 0; mi < 2; mi++) {
        s[mi][ni] = MFMA(qf[mi][0], kf0, s[mi][ni]);
        s[mi][ni] = MFMA(qf[mi][1], kf1, s[mi][ni]);
      }
    }
    for (int mi = 0; mi < 2; mi++)
      for (int j = 0; j < 4; j++) {
        float a0 = s[mi][0][j], a1 = s[mi][1][j];
        float nm = fmaxf(rmax[mi][j], fmaxf(a0, a1));
        float sc = __expf(rmax[mi][j] - nm);
        float ts = __expf(a0 - nm) + __expf(a1 - nm);
        rsum[mi][j] = rsum[mi][j] * sc + ts;
        rmax[mi][j] = nm;
      }
  }
  for (int mi = 0; mi < 2; mi++)
    for (int j = 0; j < 4; j++) {
      float gm = rmax[mi][j];
      for (int o = 1; o < 16; o <<= 1) gm = fmaxf(gm, __shfl_xor(gm, o));
      float ps = rsum[mi][j] * __expf(rmax[mi][j] - gm);
      for (int o = 1; o < 16; o <<= 1) ps += __shfl_xor(ps, o);
      if (lc == 0) {
        int m = m0 + mi * 16 + grp * 4 + j;
        Mrow[b * NN + m] = gm;
        Lrow[b * NN + m] = ps;
      }
    }
}

// ---------------- kernel 6: out = gamma * (softmax(QK^T) @ V^T) + x ----------------
// 1-wave blocks; wave tile = 32 m-rows x 128 e-cols, BN=64 per iteration.
__global__ __launch_bounds__(64, 2) void attn_out_kernel(
    const short* Q, const short* K, const short* V,
    const float* Mrow, const float* Lrow, const float* x,
    const float* gamma, float* out) {
  int b  = blockIdx.z;
  int m0 = blockIdx.y * 32;
  int e0 = blockIdx.x * 128;
  int lane = threadIdx.x;
  int lc = lane & 15, grp = lane >> 4;
  __shared__ short P_lds[32][72];   // padded stride: 144 B rows

  const short* Qb = Q + (size_t)b * NN * ND;
  const short* Kb = K + (size_t)b * NN * ND;
  const short* Vb = V + (size_t)b * NC * NN;

  bf16x8 qf[2][2];
  for (int mi = 0; mi < 2; mi++)
    for (int kk = 0; kk < 2; kk++)
      qf[mi][kk] = *(const bf16x8*)(Qb + (size_t)(m0 + mi * 16 + lc) * ND + kk * 32 + grp * 8);

  float Mr[2][4], Li[2][4];
  for (int mi = 0; mi < 2; mi++)
    for (int j = 0; j < 4; j++) {
      int m = m0 + mi * 16 + grp * 4 + j;
      Mr[mi][j] = Mrow[b * NN + m];
      Li[mi][j] = 1.0f / Lrow[b * NN + m];
    }

  f32x4 acc[2][8] = {};   // [mi][ei]

  for (int n0 = 0; n0 < NN; n0 += 64) {
    // S = Q K^T for this 32x64 tile
    f32x4 s[2][4] = {};
    for (int ni = 0; ni < 4; ni++) {
      const short* kp = Kb + (size_t)(n0 + ni * 16 + lc) * ND + grp * 8;
      bf16x8 kf0 = *(const bf16x8*)(kp);
      bf16x8 kf1 = *(const bf16x8*)(kp + 32);
      for (int mi = 0; mi < 2; mi++) {
        s[mi][ni] = MFMA(qf[mi][0], kf0, s[mi][ni]);
        s[mi][ni] = MFMA(qf[mi][1], kf1, s[mi][ni]);
      }
    }
    // P = exp(S - M) -> bf16 -> LDS (C-layout -> plain (m,n) tile)
    for (int mi = 0; mi < 2; mi++)
      for (int ni = 0; ni < 4; ni++)
        for (int j = 0; j < 4; j++) {
          float p = __expf(s[mi][ni][j] - Mr[mi][j]);
          P_lds[mi * 16 + grp * 4 + j][ni * 16 + lc] = f2bf(p);
        }
    asm volatile("s_waitcnt lgkmcnt(0)" ::: "memory");
    // read P back as A-fragments
    bf16x8 pf[2][2];
    for (int mi = 0; mi < 2; mi++) {
      pf[mi][0] = *(const bf16x8*)&P_lds[mi * 16 + lc][grp * 8];
      pf[mi][1] = *(const bf16x8*)&P_lds[mi * 16 + lc][32 + grp * 8];
    }
    // O += P @ V^T
    for (int ei = 0; ei < 8; ei++) {
      const short* vp = Vb + (size_t)(e0 + ei * 16 + lc) * NN + n0 + grp * 8;
      bf16x8 vf0 = *(const bf16x8*)(vp);
      bf16x8 vf1 = *(const bf16x8*)(vp + 32);
      for (int mi = 0; mi < 2; mi++) {
        acc[mi][ei] = MFMA(pf[mi][0], vf0, acc[mi][ei]);
        acc[mi][ei] = MFMA(pf[mi][1], vf1, acc[mi][ei]);
      }
    }
    asm volatile("s_waitcnt lgkmcnt(0)" ::: "memory"); // P_lds reads done before next overwrite
  }

  const float* xb = x + (size_t)b * NC * NN;
  float* ob = out + (size_t)b * NC * NN;
  float g = gamma[0];
  for (int mi = 0; mi < 2; mi++)
    for (int ei = 0; ei < 8; ei++) {
      int e = e0 + ei * 16 + lc;
      int mbase = m0 + mi * 16 + grp * 4;
      f32x4 xv = *(const f32x4*)(xb + (size_t)e * NN + mbase);
      f32x4 r;
      for (int j = 0; j < 4; j++)
        r[j] = g * (acc[mi][ei][j] * Li[mi][j]) + xv[j];
      *(f32x4*)(ob + (size_t)e * NN + mbase) = r;
    }
}

extern "C" void kernel_launch(void* const* d_in, const int* in_sizes, int n_in,
                              void* d_out, int out_size, void* d_ws, size_t ws_size,
                              hipStream_t stream) {
  const float* x     = (const float*)d_in[0];
  const float* Wq    = (const float*)d_in[1];
  const float* bq    = (const float*)d_in[2];
  const float* Wk    = (const float*)d_in[3];
  const float* bk    = (const float*)d_in[4];
  const float* Wv    = (const float*)d_in[5];
  const float* bv    = (const float*)d_in[6];
  const float* gamma = (const float*)d_in[7];
  float* out = (float*)d_out;

  char* ws = (char*)d_ws;
  size_t off = 0;
  auto alloc = [&](size_t bytes) {
    void* p = ws + off;
    off = (off + bytes + 255) & ~(size_t)255;
    return p;
  };
  short* xT   = (short*)alloc((size_t)NB * NN * NC * 2);   // 16 MB
  short* Wqb  = (short*)alloc((size_t)ND * NC * 2);
  short* Wkb  = (short*)alloc((size_t)ND * NC * 2);
  short* Wvb  = (short*)alloc((size_t)NC * NC * 2);
  short* Qb   = (short*)alloc((size_t)NB * NN * ND * 2);   // 2 MB
  short* Kb   = (short*)alloc((size_t)NB * NN * ND * 2);   // 2 MB
  short* Vb   = (short*)alloc((size_t)NB * NC * NN * 2);   // 16 MB
  float* Mrow = (float*)alloc((size_t)NB * NN * 4);
  float* Lrow = (float*)alloc((size_t)NB * NN * 4);

  cast_w<<<dim3(1024), dim3(256), 0, stream>>>(Wq, Wk, Wv, Wqb, Wkb, Wvb);
  transpose_x<<<dim3(NN / 32, NC / 32, NB), dim3(32, 8), 0, stream>>>(x, xT);
  proj_qk<<<dim3(NN / 64, NB), dim3(256), 0, stream>>>(xT, Wqb, Wkb, bq, bk, Qb, Kb);
  proj_v<<<dim3(NN / 128, NC / 64, NB), dim3(256), 0, stream>>>(xT, Wvb, bv, Vb);
  attn_stats<<<dim3(NN / 32, NB), dim3(64), 0, stream>>>(Qb, Kb, Mrow, Lrow);
  attn_out_kernel<<<dim3(NC / 128, NN / 32, NB), dim3(64), 0, stream>>>(
      Qb, Kb, Vb, Mrow, Lrow, x, gamma, out);
}

// Round 2
// 283.345 us; speedup vs baseline: 1.9211x; 1.9211x over previous
//
#include <hip/hip_runtime.h>

using bf16x8 = __attribute__((ext_vector_type(8))) short;
using f32x4  = __attribute__((ext_vector_type(4))) float;

#define MFMA(a,b,c) __builtin_amdgcn_mfma_f32_16x16x32_bf16((a),(b),(c),0,0,0)

static constexpr int NB = 4, NC = 512, NN = 4096, ND = 64;

__device__ __forceinline__ short f2bf(float f) {
  union { float f; unsigned u; } v; v.f = f;
  unsigned r = v.u + 0x7FFFu + ((v.u >> 16) & 1u);
  return (short)(r >> 16);
}

__device__ __forceinline__ void gld16(void* lds, const void* g) {
  __builtin_amdgcn_global_load_lds(
      (const __attribute__((address_space(1))) unsigned*)g,
      (__attribute__((address_space(3))) unsigned*)lds, 16, 0, 0);
}

// ---------------- kernel 1: cast weights to bf16 ----------------
__global__ void cast_w(const float* Wq, const float* Wk, const float* Wv,
                       short* Wqb, short* Wkb, short* Wvb) {
  int i = blockIdx.x * 256 + threadIdx.x;
  if (i < ND * NC) { Wqb[i] = f2bf(Wq[i]); Wkb[i] = f2bf(Wk[i]); }
  if (i < NC * NC) { Wvb[i] = f2bf(Wv[i]); }
}

// ---------------- kernel 2: x (B,C,N) f32 -> xT (B,N,C) bf16 ----------------
__global__ void transpose_x(const float* x, short* xT) {
  __shared__ short tile[32][34];
  int b  = blockIdx.z;
  int c0 = blockIdx.y * 32;
  int n0 = blockIdx.x * 32;
  const float* xb = x + (size_t)b * NC * NN;
  short* xTb = xT + (size_t)b * NN * NC;
  int tx = threadIdx.x, ty = threadIdx.y;
  for (int i = 0; i < 4; i++)
    tile[ty + i * 8][tx] = f2bf(xb[(size_t)(c0 + ty + i * 8) * NN + n0 + tx]);
  __syncthreads();
  for (int i = 0; i < 4; i++)
    xTb[(size_t)(n0 + ty + i * 8) * NC + c0 + tx] = tile[tx][ty + i * 8];
}

// ---------------- kernel 3: Q,K projections -> (B,N,64) bf16 ----------------
__global__ __launch_bounds__(256) void proj_qk(const short* xT, const short* Wqb, const short* Wkb,
                        const float* bq, const float* bk, short* Q, short* K) {
  int b = blockIdx.y;
  int wave = threadIdx.x >> 6, lane = threadIdx.x & 63;
  int lc = lane & 15, grp = lane >> 4;
  int n0 = blockIdx.x * 64 + wave * 16;
  const short* xTb = xT + ((size_t)b * NN + n0) * NC;
  f32x4 accq[4] = {}, acck[4] = {};
  for (int c0 = 0; c0 < NC; c0 += 32) {
    bf16x8 a = *(const bf16x8*)(xTb + (size_t)lc * NC + c0 + grp * 8);
    for (int di = 0; di < 4; di++) {
      bf16x8 wq = *(const bf16x8*)(Wqb + (size_t)(di * 16 + lc) * NC + c0 + grp * 8);
      bf16x8 wk = *(const bf16x8*)(Wkb + (size_t)(di * 16 + lc) * NC + c0 + grp * 8);
      accq[di] = MFMA(a, wq, accq[di]);
      acck[di] = MFMA(a, wk, acck[di]);
    }
  }
  short* Qb = Q + (size_t)b * NN * ND;
  short* Kb = K + (size_t)b * NN * ND;
  for (int di = 0; di < 4; di++)
    for (int j = 0; j < 4; j++) {
      int n = n0 + grp * 4 + j;
      int d = di * 16 + lc;
      Qb[(size_t)n * ND + d] = f2bf(accq[di][j] + bq[d]);
      Kb[(size_t)n * ND + d] = f2bf(acck[di][j] + bk[d]);
    }
}

// ---------------- kernel 4: V projection -> (B,C,N) bf16 ----------------
__global__ __launch_bounds__(256) void proj_v(const short* xT, const short* Wvb, const float* bv, short* V) {
  int b = blockIdx.z;
  int wave = threadIdx.x >> 6, lane = threadIdx.x & 63;
  int lc = lane & 15, grp = lane >> 4;
  int e0 = blockIdx.y * 64 + wave * 16;
  int n0 = blockIdx.x * 128;
  const short* xTb = xT + (size_t)b * NN * NC;
  f32x4 acc[8] = {};
  for (int c0 = 0; c0 < NC; c0 += 32) {
    bf16x8 a = *(const bf16x8*)(Wvb + (size_t)(e0 + lc) * NC + c0 + grp * 8);
    for (int ni = 0; ni < 8; ni++) {
      bf16x8 bfr = *(const bf16x8*)(xTb + (size_t)(n0 + ni * 16 + lc) * NC + c0 + grp * 8);
      acc[ni] = MFMA(a, bfr, acc[ni]);
    }
  }
  short* Vb = V + (size_t)b * NC * NN;
  for (int ni = 0; ni < 8; ni++)
    for (int j = 0; j < 4; j++) {
      int e = e0 + grp * 4 + j;
      int n = n0 + ni * 16 + lc;
      Vb[(size_t)e * NN + n] = f2bf(acc[ni][j] + bv[e]);
    }
}

// ---------------- kernel 5: softmax stats (4-wave, LDS-shared K) ----------------
__global__ __launch_bounds__(256, 2) void attn_stats(const short* Q, const short* K,
                                                     float* Mrow, float* Lrow) {
  __shared__ char lds[16384];   // K double buffer: 2 x 64x64 bf16
  int b = blockIdx.y;
  int tid = threadIdx.x, wave = tid >> 6, lane = tid & 63;
  int lc = lane & 15, grp = lane >> 4;
  int m0 = blockIdx.x * 128 + wave * 32;
  const short* Qb = Q + (size_t)b * NN * ND;
  const char* Kg = (const char*)(K + (size_t)b * NN * ND);

  int kR[2], kC[2];
  for (int i = 0; i < 2; i++) {
    int A = (wave * 2 + i) * 1024 + lane * 16;
    kR[i] = A >> 7;
    kC[i] = ((A >> 4) & 7) ^ (kR[i] & 7);
  }
  auto stageK = [&](char* base0, int n0) {
    for (int i = 0; i < 2; i++)
      gld16(base0 + (wave * 2 + i) * 1024,
            Kg + (size_t)(n0 + kR[i]) * 128 + kC[i] * 16);
  };

  bf16x8 qf[2][2];
  for (int mi = 0; mi < 2; mi++)
    for (int kk = 0; kk < 2; kk++)
      qf[mi][kk] = *(const bf16x8*)(Qb + (size_t)(m0 + mi * 16 + lc) * ND + kk * 32 + grp * 8);

  float rmax[2][4], rsum[2][4];
  for (int mi = 0; mi < 2; mi++)
    for (int j = 0; j < 4; j++) { rmax[mi][j] = -1e30f; rsum[mi][j] = 0.f; }

  stageK(lds, 0);
  __syncthreads();
  int cur = 0;
  for (int t = 0; t < NN / 64; t++) {
    if (t + 1 < NN / 64) stageK(lds + (cur ^ 1) * 8192, (t + 1) * 64);
    const char* Kb_l = lds + cur * 8192;
    f32x4 s[2][4] = {};
    for (int ni = 0; ni < 4; ni++) {
      int row = ni * 16 + lc;
      bf16x8 kf0 = *(const bf16x8*)(Kb_l + row * 128 + ((grp ^ (row & 7)) * 16));
      bf16x8 kf1 = *(const bf16x8*)(Kb_l + row * 128 + (((grp + 4) ^ (row & 7)) * 16));
      for (int mi = 0; mi < 2; mi++) {
        s[mi][ni] = MFMA(qf[mi][0], kf0, s[mi][ni]);
        s[mi][ni] = MFMA(qf[mi][1], kf1, s[mi][ni]);
      }
    }
    for (int mi = 0; mi < 2; mi++)
      for (int j = 0; j < 4; j++) {
        float a0 = s[mi][0][j], a1 = s[mi][1][j], a2 = s[mi][2][j], a3 = s[mi][3][j];
        float m4 = fmaxf(fmaxf(a0, a1), fmaxf(a2, a3));
        float nm = fmaxf(rmax[mi][j], m4);
        rsum[mi][j] = rsum[mi][j] * __expf(rmax[mi][j] - nm)
                    + __expf(a0 - nm) + __expf(a1 - nm) + __expf(a2 - nm) + __expf(a3 - nm);
        rmax[mi][j] = nm;
      }
    __syncthreads();
    cur ^= 1;
  }
  for (int mi = 0; mi < 2; mi++)
    for (int j = 0; j < 4; j++) {
      float gm = rmax[mi][j];
      for (int o = 1; o < 16; o <<= 1) gm = fmaxf(gm, __shfl_xor(gm, o));
      float ps = rsum[mi][j] * __expf(rmax[mi][j] - gm);
      for (int o = 1; o < 16; o <<= 1) ps += __shfl_xor(ps, o);
      if (lc == 0) {
        int m = m0 + mi * 16 + grp * 4 + j;
        Mrow[b * NN + m] = gm;
        Lrow[b * NN + m] = ps;
      }
    }
}

// ---------------- kernel 6: out = gamma * (softmax(QK^T) @ V^T) + x ----------------
// 4-wave blocks, block tile 128m x 128e, n-step 64, K/V LDS double-buffered 2-phase.
__global__ __launch_bounds__(256, 2) void attn_out_kernel(
    const short* Q, const short* K, const short* V,
    const float* Mrow, const float* Lrow, const float* x,
    const float* gamma, float* out) {
  // LDS: K dbuf 2x8KB @0, V dbuf 2x16KB @16384, P 4 waves x 4KB @49152  = 64KB
  __shared__ char lds[65536];
  int b  = blockIdx.z;
  int e0 = blockIdx.x * 128;
  int tid = threadIdx.x, wave = tid >> 6, lane = tid & 63;
  int lc = lane & 15, grp = lane >> 4;
  int m0 = blockIdx.y * 128 + wave * 32;
  char* Pw = lds + 49152 + wave * 4096;   // 32 rows x 128 B, XOR-swizzled granules

  const short* Qb = Q + (size_t)b * NN * ND;
  const char* Kg = (const char*)(K + (size_t)b * NN * ND);
  const char* Vg = (const char*)(V + (size_t)b * NC * NN);

  // staging source decomposition (linear LDS dest; inverse-swizzled global src)
  int kR[2], kC[2];
  for (int i = 0; i < 2; i++) {
    int A = (wave * 2 + i) * 1024 + lane * 16;
    kR[i] = A >> 7;
    kC[i] = ((A >> 4) & 7) ^ (kR[i] & 7);
  }
  int vR[4], vC[4];
  for (int i = 0; i < 4; i++) {
    int A = (wave * 4 + i) * 1024 + lane * 16;
    vR[i] = A >> 7;
    vC[i] = ((A >> 4) & 7) ^ (vR[i] & 7);
  }
  auto stageK = [&](char* base0, int n0) {
    for (int i = 0; i < 2; i++)
      gld16(base0 + (wave * 2 + i) * 1024,
            Kg + (size_t)(n0 + kR[i]) * 128 + kC[i] * 16);
  };
  auto stageV = [&](char* base0, int n0) {
    for (int i = 0; i < 4; i++)
      gld16(base0 + (wave * 4 + i) * 1024,
            Vg + (size_t)(e0 + vR[i]) * 8192 + (size_t)n0 * 2 + vC[i] * 16);
  };

  bf16x8 qf[2][2];
  for (int mi = 0; mi < 2; mi++)
    for (int kk = 0; kk < 2; kk++)
      qf[mi][kk] = *(const bf16x8*)(Qb + (size_t)(m0 + mi * 16 + lc) * ND + kk * 32 + grp * 8);

  float Mr[2][4], Li[2][4];
  for (int mi = 0; mi < 2; mi++)
    for (int j = 0; j < 4; j++) {
      int m = m0 + mi * 16 + grp * 4 + j;
      Mr[mi][j] = Mrow[b * NN + m];
      Li[mi][j] = 1.0f / Lrow[b * NN + m];
    }

  f32x4 acc[2][8] = {};   // [mi][ei] -> 32m x 128e

  stageK(lds, 0);
  stageV(lds + 16384, 0);
  __syncthreads();
  int cur = 0;
  for (int t = 0; t < NN / 64; t++) {
    if (t + 1 < NN / 64) {
      stageK(lds + (cur ^ 1) * 8192, (t + 1) * 64);
      stageV(lds + 16384 + (cur ^ 1) * 16384, (t + 1) * 64);
    }
    const char* Kb_l = lds + cur * 8192;
    const char* Vb_l = lds + 16384 + cur * 16384;

    // S = Q K^T (32 x 64)
    f32x4 s[2][4] = {};
    for (int ni = 0; ni < 4; ni++) {
      int row = ni * 16 + lc;
      bf16x8 kf0 = *(const bf16x8*)(Kb_l + row * 128 + ((grp ^ (row & 7)) * 16));
      bf16x8 kf1 = *(const bf16x8*)(Kb_l + row * 128 + (((grp + 4) ^ (row & 7)) * 16));
      for (int mi = 0; mi < 2; mi++) {
        s[mi][ni] = MFMA(qf[mi][0], kf0, s[mi][ni]);
        s[mi][ni] = MFMA(qf[mi][1], kf1, s[mi][ni]);
      }
    }
    // P = exp(S - M) -> bf16 -> per-wave LDS tile (granule-XOR-swizzled, stride 128B)
    for (int mi = 0; mi < 2; mi++)
      for (int ni = 0; ni < 4; ni++)
        for (int j = 0; j < 4; j++) {
          int row = mi * 16 + grp * 4 + j;
          int gran = ni * 2 + (lc >> 3);
          int off = row * 128 + ((gran ^ (row & 7)) * 16) + (lc & 7) * 2;
          float p = __expf(s[mi][ni][j] - Mr[mi][j]);
          *(short*)(Pw + off) = f2bf(p);
        }
    asm volatile("s_waitcnt lgkmcnt(0)" ::: "memory");
    // read P as A-fragments (same swizzle)
    bf16x8 pf[2][2];
    for (int mi = 0; mi < 2; mi++)
      for (int ks = 0; ks < 2; ks++) {
        int row = mi * 16 + lc;
        int gran = ks * 4 + grp;
        pf[mi][ks] = *(const bf16x8*)(Pw + row * 128 + ((gran ^ (row & 7)) * 16));
      }
    // O += P @ V^T
    for (int ei = 0; ei < 8; ei++) {
      int row = ei * 16 + lc;
      bf16x8 vf0 = *(const bf16x8*)(Vb_l + row * 128 + ((grp ^ (row & 7)) * 16));
      bf16x8 vf1 = *(const bf16x8*)(Vb_l + row * 128 + (((grp + 4) ^ (row & 7)) * 16));
      for (int mi = 0; mi < 2; mi++) {
        acc[mi][ei] = MFMA(pf[mi][0], vf0, acc[mi][ei]);
        acc[mi][ei] = MFMA(pf[mi][1], vf1, acc[mi][ei]);
      }
    }
    __syncthreads();   // drains vmcnt (next tile staged) + lgkm before buffer swap
    cur ^= 1;
  }

  const float* xb = x + (size_t)b * NC * NN;
  float* ob = out + (size_t)b * NC * NN;
  float g = gamma[0];
  for (int mi = 0; mi < 2; mi++)
    for (int ei = 0; ei < 8; ei++) {
      int e = e0 + ei * 16 + lc;
      int mbase = m0 + mi * 16 + grp * 4;
      f32x4 xv = *(const f32x4*)(xb + (size_t)e * NN + mbase);
      f32x4 r;
      for (int j = 0; j < 4; j++)
        r[j] = g * (acc[mi][ei][j] * Li[mi][j]) + xv[j];
      *(f32x4*)(ob + (size_t)e * NN + mbase) = r;
    }
}

extern "C" void kernel_launch(void* const* d_in, const int* in_sizes, int n_in,
                              void* d_out, int out_size, void* d_ws, size_t ws_size,
                              hipStream_t stream) {
  const float* x     = (const float*)d_in[0];
  const float* Wq    = (const float*)d_in[1];
  const float* bq    = (const float*)d_in[2];
  const float* Wk    = (const float*)d_in[3];
  const float* bk    = (const float*)d_in[4];
  const float* Wv    = (const float*)d_in[5];
  const float* bv    = (const float*)d_in[6];
  const float* gamma = (const float*)d_in[7];
  float* out = (float*)d_out;

  char* ws = (char*)d_ws;
  size_t off = 0;
  auto alloc = [&](size_t bytes) {
    void* p = ws + off;
    off = (off + bytes + 255) & ~(size_t)255;
    return p;
  };
  short* xT   = (short*)alloc((size_t)NB * NN * NC * 2);   // 16 MB
  short* Wqb  = (short*)alloc((size_t)ND * NC * 2);
  short* Wkb  = (short*)alloc((size_t)ND * NC * 2);
  short* Wvb  = (short*)alloc((size_t)NC * NC * 2);
  short* Qb   = (short*)alloc((size_t)NB * NN * ND * 2);   // 2 MB
  short* Kb   = (short*)alloc((size_t)NB * NN * ND * 2);   // 2 MB
  short* Vb   = (short*)alloc((size_t)NB * NC * NN * 2);   // 16 MB
  float* Mrow = (float*)alloc((size_t)NB * NN * 4);
  float* Lrow = (float*)alloc((size_t)NB * NN * 4);

  cast_w<<<dim3(1024), dim3(256), 0, stream>>>(Wq, Wk, Wv, Wqb, Wkb, Wvb);
  transpose_x<<<dim3(NN / 32, NC / 32, NB), dim3(32, 8), 0, stream>>>(x, xT);
  proj_qk<<<dim3(NN / 64, NB), dim3(256), 0, stream>>>(xT, Wqb, Wkb, bq, bk, Qb, Kb);
  proj_v<<<dim3(NN / 128, NC / 64, NB), dim3(256), 0, stream>>>(xT, Wvb, bv, Vb);
  attn_stats<<<dim3(NN / 128, NB), dim3(256), 0, stream>>>(Qb, Kb, Mrow, Lrow);
  attn_out_kernel<<<dim3(NC / 128, NN / 128, NB), dim3(256), 0, stream>>>(
      Qb, Kb, Vb, Mrow, Lrow, x, gamma, out);
}

// Round 3
// 270.024 us; speedup vs baseline: 2.0159x; 1.0493x over previous
//
#include <hip/hip_runtime.h>

using bf16x8 = __attribute__((ext_vector_type(8))) short;
using f32x4  = __attribute__((ext_vector_type(4))) float;

#define MFMA(a,b,c) __builtin_amdgcn_mfma_f32_16x16x32_bf16((a),(b),(c),0,0,0)

static constexpr int NB = 4, NC = 512, NN = 4096, ND = 64;
static constexpr float LOG2E = 1.4426950408889634f;

__device__ __forceinline__ short f2bf(float f) {
  union { float f; unsigned u; } v; v.f = f;
  unsigned r = v.u + 0x7FFFu + ((v.u >> 16) & 1u);
  return (short)(r >> 16);
}

__device__ __forceinline__ void gld16(void* lds, const void* g) {
  __builtin_amdgcn_global_load_lds(
      (const __attribute__((address_space(1))) unsigned*)g,
      (__attribute__((address_space(3))) unsigned*)lds, 16, 0, 0);
}

// ---------------- kernel 1: cast weights to bf16 ----------------
__global__ void cast_w(const float* Wq, const float* Wk, const float* Wv,
                       short* Wqb, short* Wkb, short* Wvb) {
  int i = blockIdx.x * 256 + threadIdx.x;
  if (i < ND * NC) { Wqb[i] = f2bf(Wq[i]); Wkb[i] = f2bf(Wk[i]); }
  if (i < NC * NC) { Wvb[i] = f2bf(Wv[i]); }
}

// ---------------- kernel 2: x (B,C,N) f32 -> xT (B,N,C) bf16 (LDS-free) ------
// lane handles one (n, 8c) octet: 8 coalesced-by-column scalar loads, one 16B store.
__global__ __launch_bounds__(256) void transpose_x(const float* x, short* xT) {
  int b = blockIdx.z, c0 = blockIdx.y * 32, n0 = blockIdx.x * 64;
  int tid = threadIdx.x;
  int n = n0 + (tid >> 2);
  int c = c0 + (tid & 3) * 8;
  const float* xb = x + (size_t)b * NC * NN;
  bf16x8 v;
  #pragma unroll
  for (int i = 0; i < 8; i++) v[i] = f2bf(xb[(size_t)(c + i) * NN + n]);
  *(bf16x8*)(xT + ((size_t)b * NN + n) * NC + c) = v;
}

// ---------------- kernel 3: Q,K projections -> (B,N,64) bf16 ----------------
// Q is pre-scaled by log2(e) so downstream softmax uses exp2.
__global__ __launch_bounds__(256) void proj_qk(const short* xT, const short* Wqb, const short* Wkb,
                        const float* bq, const float* bk, short* Q, short* K) {
  int b = blockIdx.y;
  int wave = threadIdx.x >> 6, lane = threadIdx.x & 63;
  int lc = lane & 15, grp = lane >> 4;
  int n0 = blockIdx.x * 64 + wave * 16;
  const short* xTb = xT + ((size_t)b * NN + n0) * NC;
  f32x4 accq[4] = {}, acck[4] = {};
  for (int c0 = 0; c0 < NC; c0 += 32) {
    bf16x8 a = *(const bf16x8*)(xTb + (size_t)lc * NC + c0 + grp * 8);
    #pragma unroll
    for (int di = 0; di < 4; di++) {
      bf16x8 wq = *(const bf16x8*)(Wqb + (size_t)(di * 16 + lc) * NC + c0 + grp * 8);
      bf16x8 wk = *(const bf16x8*)(Wkb + (size_t)(di * 16 + lc) * NC + c0 + grp * 8);
      accq[di] = MFMA(a, wq, accq[di]);
      acck[di] = MFMA(a, wk, acck[di]);
    }
  }
  short* Qb = Q + (size_t)b * NN * ND;
  short* Kb = K + (size_t)b * NN * ND;
  #pragma unroll
  for (int di = 0; di < 4; di++)
    #pragma unroll
    for (int j = 0; j < 4; j++) {
      int n = n0 + grp * 4 + j;
      int d = di * 16 + lc;
      Qb[(size_t)n * ND + d] = f2bf((accq[di][j] + bq[d]) * LOG2E);
      Kb[(size_t)n * ND + d] = f2bf(acck[di][j] + bk[d]);
    }
}

// ---------------- kernel 4: V projection -> (B,C,N) bf16 (LDS-staged GEMM) ----
__global__ __launch_bounds__(256, 2) void proj_v(const short* xT, const short* Wvb,
                                                 const float* bv, short* V) {
  __shared__ char lds[65536];   // dbuf: [Wv 16K | xT 16K] x2
  int b = blockIdx.z;
  int tid = threadIdx.x, wv = tid >> 6, lane = tid & 63;
  int lc = lane & 15, grp = lane >> 4;
  int e0 = blockIdx.y * 128;
  int n0 = blockIdx.x * 128;
  const char* Wg = (const char*)Wvb;
  const char* Xg = (const char*)(xT + (size_t)b * NN * NC);
  int eq = (wv >> 1) * 64, nq = (wv & 1) * 64;

  auto stage = [&](int t) {
    char* buf = lds + (t & 1) * 32768;
    int c0 = t * 64;
    #pragma unroll
    for (int i = 0; i < 4; i++) {
      int r = wv * 32 + i * 8 + (lane >> 3), g = lane & 7;
      gld16(buf + wv * 4096 + i * 1024 + lane * 16,
            Wg + (size_t)(e0 + r) * 1024 + (size_t)c0 * 2 + ((g ^ (r & 7)) * 16));
    }
    #pragma unroll
    for (int i = 0; i < 4; i++) {
      int r = wv * 32 + i * 8 + (lane >> 3), g = lane & 7;
      gld16(buf + 16384 + wv * 4096 + i * 1024 + lane * 16,
            Xg + (size_t)(n0 + r) * 1024 + (size_t)c0 * 2 + ((g ^ (r & 7)) * 16));
    }
  };

  f32x4 acc[4][4] = {};
  stage(0);
  for (int t = 0; t < 8; t++) {
    asm volatile("s_waitcnt vmcnt(0)" ::: "memory");
    __builtin_amdgcn_sched_barrier(0);
    __builtin_amdgcn_s_barrier();
    if (t < 7) stage(t + 1);
    const char* buf = lds + (t & 1) * 32768;
    bf16x8 wf[4][2], xf[4][2];
    #pragma unroll
    for (int mi = 0; mi < 4; mi++)
      #pragma unroll
      for (int ks = 0; ks < 2; ks++) {
        int r = eq + mi * 16 + lc;
        wf[mi][ks] = *(const bf16x8*)(buf + r * 128 + (((ks * 4 + grp) ^ (r & 7)) * 16));
      }
    #pragma unroll
    for (int ni = 0; ni < 4; ni++)
      #pragma unroll
      for (int ks = 0; ks < 2; ks++) {
        int r = nq + ni * 16 + lc;
        xf[ni][ks] = *(const bf16x8*)(buf + 16384 + r * 128 + (((ks * 4 + grp) ^ (r & 7)) * 16));
      }
    #pragma unroll
    for (int mi = 0; mi < 4; mi++)
      #pragma unroll
      for (int ni = 0; ni < 4; ni++) {
        acc[mi][ni] = MFMA(wf[mi][0], xf[ni][0], acc[mi][ni]);
        acc[mi][ni] = MFMA(wf[mi][1], xf[ni][1], acc[mi][ni]);
      }
  }
  short* Vbp = V + (size_t)b * NC * NN;
  #pragma unroll
  for (int mi = 0; mi < 4; mi++)
    #pragma unroll
    for (int j = 0; j < 4; j++) {
      int e = e0 + eq + mi * 16 + grp * 4 + j;
      float bb = bv[e];
      #pragma unroll
      for (int ni = 0; ni < 4; ni++) {
        int n = n0 + nq + ni * 16 + lc;
        Vbp[(size_t)e * NN + n] = f2bf(acc[mi][ni][j] + bb);
      }
    }
}

// ---------------- kernel 5: softmax stats, n-split partials ----------------
__global__ __launch_bounds__(256, 2) void attn_stats(const short* Q, const short* K,
                                                     float* Mp, float* Lp) {
  __shared__ char lds[16384];
  int b = blockIdx.y, nh = blockIdx.z;
  int tid = threadIdx.x, wave = tid >> 6, lane = tid & 63;
  int lc = lane & 15, grp = lane >> 4;
  int m0 = blockIdx.x * 128 + wave * 32;
  const short* Qb = Q + (size_t)b * NN * ND;
  const char* Kg = (const char*)(K + (size_t)b * NN * ND);

  int kR[2], kC[2];
  #pragma unroll
  for (int i = 0; i < 2; i++) {
    int A = (wave * 2 + i) * 1024 + lane * 16;
    kR[i] = A >> 7;
    kC[i] = ((A >> 4) & 7) ^ (kR[i] & 7);
  }
  auto stageK = [&](char* base0, int n0) {
    #pragma unroll
    for (int i = 0; i < 2; i++)
      gld16(base0 + (wave * 2 + i) * 1024,
            Kg + (size_t)(n0 + kR[i]) * 128 + kC[i] * 16);
  };

  bf16x8 qf[2][2];
  #pragma unroll
  for (int mi = 0; mi < 2; mi++)
    #pragma unroll
    for (int kk = 0; kk < 2; kk++)
      qf[mi][kk] = *(const bf16x8*)(Qb + (size_t)(m0 + mi * 16 + lc) * ND + kk * 32 + grp * 8);

  float rmax[2][4], rsum[2][4];
  #pragma unroll
  for (int mi = 0; mi < 2; mi++)
    #pragma unroll
    for (int j = 0; j < 4; j++) { rmax[mi][j] = -1e30f; rsum[mi][j] = 0.f; }

  stageK(lds, nh * 2048);
  __syncthreads();
  int cur = 0;
  for (int tt = 0; tt < 32; tt++) {
    int t = nh * 32 + tt;
    if (tt + 1 < 32) stageK(lds + (cur ^ 1) * 8192, (t + 1) * 64);
    const char* Kb_l = lds + cur * 8192;
    f32x4 s[2][4] = {};
    #pragma unroll
    for (int ni = 0; ni < 4; ni++) {
      int row = ni * 16 + lc;
      bf16x8 kf0 = *(const bf16x8*)(Kb_l + row * 128 + ((grp ^ (row & 7)) * 16));
      bf16x8 kf1 = *(const bf16x8*)(Kb_l + row * 128 + (((grp + 4) ^ (row & 7)) * 16));
      #pragma unroll
      for (int mi = 0; mi < 2; mi++) {
        s[mi][ni] = MFMA(qf[mi][0], kf0, s[mi][ni]);
        s[mi][ni] = MFMA(qf[mi][1], kf1, s[mi][ni]);
      }
    }
    #pragma unroll
    for (int mi = 0; mi < 2; mi++)
      #pragma unroll
      for (int j = 0; j < 4; j++) {
        float a0 = s[mi][0][j], a1 = s[mi][1][j], a2 = s[mi][2][j], a3 = s[mi][3][j];
        float m4 = fmaxf(fmaxf(a0, a1), fmaxf(a2, a3));
        float nm = fmaxf(rmax[mi][j], m4);
        rsum[mi][j] = rsum[mi][j] * exp2f(rmax[mi][j] - nm)
                    + exp2f(a0 - nm) + exp2f(a1 - nm) + exp2f(a2 - nm) + exp2f(a3 - nm);
        rmax[mi][j] = nm;
      }
    __syncthreads();
    cur ^= 1;
  }
  #pragma unroll
  for (int mi = 0; mi < 2; mi++)
    #pragma unroll
    for (int j = 0; j < 4; j++) {
      float gm = rmax[mi][j];
      for (int o = 1; o < 16; o <<= 1) gm = fmaxf(gm, __shfl_xor(gm, o));
      float ps = rsum[mi][j] * exp2f(rmax[mi][j] - gm);
      for (int o = 1; o < 16; o <<= 1) ps += __shfl_xor(ps, o);
      if (lc == 0) {
        int m = m0 + mi * 16 + grp * 4 + j;
        Mp[((size_t)nh * NB + b) * NN + m] = gm;
        Lp[((size_t)nh * NB + b) * NN + m] = ps;
      }
    }
}

__global__ void stats_combine(const float* Mp, const float* Lp, float* Mrow, float* Lrow) {
  int i = blockIdx.x * 256 + threadIdx.x;
  if (i >= NB * NN) return;
  float m0 = Mp[i], m1 = Mp[NB * NN + i];
  float M = fmaxf(m0, m1);
  float L = Lp[i] * exp2f(m0 - M) + Lp[NB * NN + i] * exp2f(m1 - M);
  Mrow[i] = M; Lrow[i] = L;
}

// ---------------- kernel 6: out = gamma * (softmax(QK^T) @ V^T) + x ----------
// Block = 64 m-rows x 512 e (full C). 4 waves; wave w: e in [w*128,(w+1)*128).
// P computed once per m-row. K & V staging wave-private (no barriers, counted vmcnt);
// P shared via 2 lgkm-only barriers per step. LDS: K 8K | P 8K | V 4x16K = 80KB.
__global__ __launch_bounds__(256, 2) void attn_out_kernel(
    const short* Q, const short* K, const short* V,
    const float* Mrow, const float* Lrow, const float* x,
    const float* gamma, float* out) {
  __shared__ char lds[81920];
  int bid = blockIdx.x;
  int b = (bid & 7) >> 1;                  // batch -> XCD pair (L2 locality for V)
  int mblk = (bid >> 3) * 2 + (bid & 1);
  int m0 = mblk * 64;
  int tid = threadIdx.x, wv = tid >> 6, lane = tid & 63;
  int lc = lane & 15, grp = lane >> 4;
  int we0 = wv * 128;

  char* Kl = lds;                 // 64n x 64d, swizzled 128B rows
  char* Pl = lds + 8192;          // 64m x 64n, swizzled 128B rows
  char* bufA = lds + 16384 + wv * 16384;        // wave-private V: 64e x 64n
  char* bufB = bufA + 8192;

  const short* Qb = Q + (size_t)b * NN * ND;
  const char* Kg = (const char*)(K + (size_t)b * NN * ND);
  const char* Vg = (const char*)(V + (size_t)b * NC * NN);

  // ---- prologue loads (issued BEFORE staging so their drain keeps stages in flight)
  bf16x8 qf[4][2];
  #pragma unroll
  for (int mi = 0; mi < 4; mi++)
    #pragma unroll
    for (int ks = 0; ks < 2; ks++)
      qf[mi][ks] = *(const bf16x8*)(Qb + (size_t)(m0 + mi * 16 + lc) * ND + ks * 32 + grp * 8);
  float Mr[4][4];
  #pragma unroll
  for (int mi = 0; mi < 4; mi++)
    #pragma unroll
    for (int j = 0; j < 4; j++)
      Mr[mi][j] = Mrow[(size_t)b * NN + m0 + mi * 16 + grp * 4 + j];

  auto stageV = [&](char* dst, int eBase, int n0) {
    #pragma unroll
    for (int i = 0; i < 8; i++) {
      int r = i * 8 + (lane >> 3), g = lane & 7;
      gld16(dst + i * 1024 + lane * 16,
            Vg + (size_t)(eBase + r) * 8192 + (size_t)n0 * 2 + ((g ^ (r & 7)) * 16));
    }
  };
  auto stageK = [&](int n0) {
    #pragma unroll
    for (int i = 0; i < 2; i++) {
      int r = wv * 16 + i * 8 + (lane >> 3), g = lane & 7;
      gld16(Kl + wv * 2048 + i * 1024 + lane * 16,
            Kg + (size_t)(n0 + r) * 128 + ((g ^ (r & 7)) * 16));
    }
  };

  f32x4 acc[4][8] = {};   // [mi][ei]: 64m x 128e per wave

  stageK(0);              // +2
  stageV(bufA, we0, 0);   // +8
  for (int t = 0; t < 64; t++) {
    int n0 = t * 64, n1 = ((t + 1) & 63) * 64;
    // K(t) landed (leave VA in flight)
    asm volatile("s_waitcnt vmcnt(8)" ::: "memory");
    __builtin_amdgcn_sched_barrier(0);
    stageV(bufB, we0 + 64, n0);          // e-high of current step
    // ---- S = Q K^T for n-stripe wv (wave-private K rows)
    int kr = wv * 16 + lc;
    bf16x8 kf0 = *(const bf16x8*)(Kl + kr * 128 + ((grp ^ (kr & 7)) * 16));
    bf16x8 kf1 = *(const bf16x8*)(Kl + kr * 128 + (((4 + grp) ^ (kr & 7)) * 16));
    f32x4 s[4] = {};
    #pragma unroll
    for (int mi = 0; mi < 4; mi++) {
      s[mi] = MFMA(qf[mi][0], kf0, s[mi]);
      s[mi] = MFMA(qf[mi][1], kf1, s[mi]);
    }
    // ---- P = exp2(S - M) -> shared P tile (swizzled)
    #pragma unroll
    for (int mi = 0; mi < 4; mi++)
      #pragma unroll
      for (int j = 0; j < 4; j++) {
        int row = mi * 16 + grp * 4 + j;
        int sg = (wv * 2 + (lc >> 3)) ^ (row & 7);
        *(short*)(Pl + row * 128 + sg * 16 + (lc & 7) * 2) =
            f2bf(exp2f(s[mi][j] - Mr[mi][j]));
      }
    asm volatile("s_waitcnt lgkmcnt(0)" ::: "memory");
    __builtin_amdgcn_sched_barrier(0);
    __builtin_amdgcn_s_barrier();        // P(t) visible
    bf16x8 pf[4][2];
    #pragma unroll
    for (int mi = 0; mi < 4; mi++)
      #pragma unroll
      for (int ks = 0; ks < 2; ks++) {
        int row = mi * 16 + lc;
        pf[mi][ks] = *(const bf16x8*)(Pl + row * 128 + (((ks * 4 + grp) ^ (row & 7)) * 16));
      }
    asm volatile("s_waitcnt lgkmcnt(0)" ::: "memory");
    __builtin_amdgcn_sched_barrier(0);
    __builtin_amdgcn_s_barrier();        // all waves done reading P(t)
    stageK(n1);                          // wave-private K prefetch (+2)
    // VA(t) landed (VB + K(t+1) = 10 stay in flight)
    asm volatile("s_waitcnt vmcnt(10)" ::: "memory");
    __builtin_amdgcn_sched_barrier(0);
    #pragma unroll
    for (int e4 = 0; e4 < 4; e4++) {
      int r = e4 * 16 + lc;
      bf16x8 v0 = *(const bf16x8*)(bufA + r * 128 + ((grp ^ (r & 7)) * 16));
      bf16x8 v1 = *(const bf16x8*)(bufA + r * 128 + (((4 + grp) ^ (r & 7)) * 16));
      #pragma unroll
      for (int mi = 0; mi < 4; mi++) {
        acc[mi][e4] = MFMA(pf[mi][0], v0, acc[mi][e4]);
        acc[mi][e4] = MFMA(pf[mi][1], v1, acc[mi][e4]);
      }
    }
    asm volatile("s_waitcnt lgkmcnt(0)" ::: "memory");   // bufA reads drained
    __builtin_amdgcn_sched_barrier(0);
    stageV(bufA, we0, n1);               // e-low of next step (+8)
    // VB(t) landed (K(t+1) + VA(t+1) = 10 stay in flight)
    asm volatile("s_waitcnt vmcnt(10)" ::: "memory");
    __builtin_amdgcn_sched_barrier(0);
    #pragma unroll
    for (int e4 = 0; e4 < 4; e4++) {
      int r = e4 * 16 + lc;
      bf16x8 v0 = *(const bf16x8*)(bufB + r * 128 + ((grp ^ (r & 7)) * 16));
      bf16x8 v1 = *(const bf16x8*)(bufB + r * 128 + (((4 + grp) ^ (r & 7)) * 16));
      #pragma unroll
      for (int mi = 0; mi < 4; mi++) {
        acc[mi][4 + e4] = MFMA(pf[mi][0], v0, acc[mi][4 + e4]);
        acc[mi][4 + e4] = MFMA(pf[mi][1], v1, acc[mi][4 + e4]);
      }
    }
  }
  asm volatile("s_waitcnt vmcnt(0)" ::: "memory");   // drain dummy prefetches
  __builtin_amdgcn_sched_barrier(0);

  // ---- epilogue: out[e][m] = gamma * acc/L + x
  float Li[4][4];
  #pragma unroll
  for (int mi = 0; mi < 4; mi++)
    #pragma unroll
    for (int j = 0; j < 4; j++)
      Li[mi][j] = 1.0f / Lrow[(size_t)b * NN + m0 + mi * 16 + grp * 4 + j];
  const float* xb = x + (size_t)b * NC * NN;
  float* ob = out + (size_t)b * NC * NN;
  float g = gamma[0];
  #pragma unroll
  for (int mi = 0; mi < 4; mi++)
    #pragma unroll
    for (int ei = 0; ei < 8; ei++) {
      int e = we0 + ei * 16 + lc;
      int mbase = m0 + mi * 16 + grp * 4;
      f32x4 xv = *(const f32x4*)(xb + (size_t)e * NN + mbase);
      f32x4 r;
      #pragma unroll
      for (int j = 0; j < 4; j++)
        r[j] = g * (acc[mi][ei][j] * Li[mi][j]) + xv[j];
      *(f32x4*)(ob + (size_t)e * NN + mbase) = r;
    }
}

extern "C" void kernel_launch(void* const* d_in, const int* in_sizes, int n_in,
                              void* d_out, int out_size, void* d_ws, size_t ws_size,
                              hipStream_t stream) {
  const float* x     = (const float*)d_in[0];
  const float* Wq    = (const float*)d_in[1];
  const float* bq    = (const float*)d_in[2];
  const float* Wk    = (const float*)d_in[3];
  const float* bk    = (const float*)d_in[4];
  const float* Wv    = (const float*)d_in[5];
  const float* bv    = (const float*)d_in[6];
  const float* gamma = (const float*)d_in[7];
  float* out = (float*)d_out;

  char* ws = (char*)d_ws;
  size_t off = 0;
  auto alloc = [&](size_t bytes) {
    void* p = ws + off;
    off = (off + bytes + 255) & ~(size_t)255;
    return p;
  };
  short* xT   = (short*)alloc((size_t)NB * NN * NC * 2);   // 16 MB
  short* Wqb  = (short*)alloc((size_t)ND * NC * 2);
  short* Wkb  = (short*)alloc((size_t)ND * NC * 2);
  short* Wvb  = (short*)alloc((size_t)NC * NC * 2);
  short* Qb   = (short*)alloc((size_t)NB * NN * ND * 2);   // 2 MB
  short* Kb   = (short*)alloc((size_t)NB * NN * ND * 2);   // 2 MB
  short* Vb   = (short*)alloc((size_t)NB * NC * NN * 2);   // 16 MB
  float* Mrow = (float*)alloc((size_t)NB * NN * 4);
  float* Lrow = (float*)alloc((size_t)NB * NN * 4);
  float* Mp   = (float*)alloc((size_t)2 * NB * NN * 4);
  float* Lp   = (float*)alloc((size_t)2 * NB * NN * 4);

  cast_w<<<dim3(1024), dim3(256), 0, stream>>>(Wq, Wk, Wv, Wqb, Wkb, Wvb);
  transpose_x<<<dim3(NN / 64, NC / 32, NB), dim3(256), 0, stream>>>(x, xT);
  proj_qk<<<dim3(NN / 64, NB), dim3(256), 0, stream>>>(xT, Wqb, Wkb, bq, bk, Qb, Kb);
  proj_v<<<dim3(NN / 128, NC / 128, NB), dim3(256), 0, stream>>>(xT, Wvb, bv, Vb);
  attn_stats<<<dim3(NN / 128, NB, 2), dim3(256), 0, stream>>>(Qb, Kb, Mp, Lp);
  stats_combine<<<dim3(NB * NN / 256), dim3(256), 0, stream>>>(Mp, Lp, Mrow, Lrow);
  attn_out_kernel<<<dim3(256), dim3(256), 0, stream>>>(
      Qb, Kb, Vb, Mrow, Lrow, x, gamma, out);
}

// Round 4
// 249.938 us; speedup vs baseline: 2.1779x; 1.0804x over previous
//
#include <hip/hip_runtime.h>
#include <math.h>

using bf16x8 = __attribute__((ext_vector_type(8))) short;
using f32x4  = __attribute__((ext_vector_type(4))) float;

#define MFMA(a,b,c) __builtin_amdgcn_mfma_f32_16x16x32_bf16((a),(b),(c),0,0,0)

static constexpr int NB = 4, NC = 512, NN = 4096, ND = 64;
static constexpr float LOG2E = 1.4426950408889634f;

__device__ __forceinline__ short f2bf(float f) {
  union { float f; unsigned u; } v; v.f = f;
  unsigned r = v.u + 0x7FFFu + ((v.u >> 16) & 1u);
  return (short)(r >> 16);
}

__device__ __forceinline__ unsigned cvt_pk_bf16(float a, float b) {
  unsigned r;
  asm("v_cvt_pk_bf16_f32 %0, %1, %2" : "=v"(r) : "v"(a), "v"(b));
  return r;
}

__device__ __forceinline__ void gld16(void* lds, const void* g) {
  __builtin_amdgcn_global_load_lds(
      (const __attribute__((address_space(1))) unsigned*)g,
      (__attribute__((address_space(3))) unsigned*)lds, 16, 0, 0);
}

// ---------------- kernel 1: cast weights to bf16 ----------------
__global__ void cast_w(const float* Wq, const float* Wk, const float* Wv,
                       short* Wqb, short* Wkb, short* Wvb) {
  int i = blockIdx.x * 256 + threadIdx.x;
  if (i < ND * NC) { Wqb[i] = f2bf(Wq[i]); Wkb[i] = f2bf(Wk[i]); }
  if (i < NC * NC) { Wvb[i] = f2bf(Wv[i]); }
}

// ---------------- kernel 2: x (B,C,N) f32 -> xT (B,N,C) bf16 (LDS-free) ------
__global__ __launch_bounds__(256) void transpose_x(const float* x, short* xT) {
  int b = blockIdx.z, c0 = blockIdx.y * 32, n0 = blockIdx.x * 64;
  int tid = threadIdx.x;
  int n = n0 + (tid >> 2);
  int c = c0 + (tid & 3) * 8;
  const float* xb = x + (size_t)b * NC * NN;
  bf16x8 v;
  #pragma unroll
  for (int i = 0; i < 8; i++) v[i] = f2bf(xb[(size_t)(c + i) * NN + n]);
  *(bf16x8*)(xT + ((size_t)b * NN + n) * NC + c) = v;
}

// ---------------- kernel 3: Q,K projections -> (B,N,64) bf16 ----------------
// Q pre-scaled by log2(e): downstream softmax uses exp2.
__global__ __launch_bounds__(256) void proj_qk(const short* xT, const short* Wqb, const short* Wkb,
                        const float* bq, const float* bk, short* Q, short* K) {
  int b = blockIdx.y;
  int wave = threadIdx.x >> 6, lane = threadIdx.x & 63;
  int lc = lane & 15, grp = lane >> 4;
  int n0 = blockIdx.x * 64 + wave * 16;
  const short* xTb = xT + ((size_t)b * NN + n0) * NC;
  f32x4 accq[4] = {}, acck[4] = {};
  for (int c0 = 0; c0 < NC; c0 += 32) {
    bf16x8 a = *(const bf16x8*)(xTb + (size_t)lc * NC + c0 + grp * 8);
    #pragma unroll
    for (int di = 0; di < 4; di++) {
      bf16x8 wq = *(const bf16x8*)(Wqb + (size_t)(di * 16 + lc) * NC + c0 + grp * 8);
      bf16x8 wk = *(const bf16x8*)(Wkb + (size_t)(di * 16 + lc) * NC + c0 + grp * 8);
      accq[di] = MFMA(a, wq, accq[di]);
      acck[di] = MFMA(a, wk, acck[di]);
    }
  }
  short* Qb = Q + (size_t)b * NN * ND;
  short* Kb = K + (size_t)b * NN * ND;
  #pragma unroll
  for (int di = 0; di < 4; di++)
    #pragma unroll
    for (int j = 0; j < 4; j++) {
      int n = n0 + grp * 4 + j;
      int d = di * 16 + lc;
      Qb[(size_t)n * ND + d] = f2bf((accq[di][j] + bq[d]) * LOG2E);
      Kb[(size_t)n * ND + d] = f2bf(acck[di][j] + bk[d]);
    }
}

// ---------------- kernel 4: V projection -> (B,C,N) bf16, pi-permuted cols ----
// Vp[e][32t + kap] = V[e][32t + pi(kap)], pi(k)=16*((k>>2)&1)+4*(k>>3)+(k&3).
// Inverse: value at n (nu = n&31) goes to kap = 8*((nu>>2)&3)+4*((nu>>4)&1)+(nu&3).
__global__ __launch_bounds__(256, 2) void proj_v(const short* xT, const short* Wvb,
                                                 const float* bv, short* V) {
  __shared__ char lds[65536];   // dbuf: [Wv 16K | xT 16K] x2
  int b = blockIdx.z;
  int tid = threadIdx.x, wv = tid >> 6, lane = tid & 63;
  int lc = lane & 15, grp = lane >> 4;
  int e0 = blockIdx.y * 128;
  int n0 = blockIdx.x * 128;
  const char* Wg = (const char*)Wvb;
  const char* Xg = (const char*)(xT + (size_t)b * NN * NC);
  int eq = (wv >> 1) * 64, nq = (wv & 1) * 64;

  auto stage = [&](int t) {
    char* buf = lds + (t & 1) * 32768;
    int c0 = t * 64;
    #pragma unroll
    for (int i = 0; i < 4; i++) {
      int r = wv * 32 + i * 8 + (lane >> 3), g = lane & 7;
      gld16(buf + wv * 4096 + i * 1024 + lane * 16,
            Wg + (size_t)(e0 + r) * 1024 + (size_t)c0 * 2 + ((g ^ (r & 7)) * 16));
    }
    #pragma unroll
    for (int i = 0; i < 4; i++) {
      int r = wv * 32 + i * 8 + (lane >> 3), g = lane & 7;
      gld16(buf + 16384 + wv * 4096 + i * 1024 + lane * 16,
            Xg + (size_t)(n0 + r) * 1024 + (size_t)c0 * 2 + ((g ^ (r & 7)) * 16));
    }
  };

  f32x4 acc[4][4] = {};
  stage(0);
  for (int t = 0; t < 8; t++) {
    asm volatile("s_waitcnt vmcnt(0)" ::: "memory");
    __builtin_amdgcn_sched_barrier(0);
    __builtin_amdgcn_s_barrier();
    if (t < 7) stage(t + 1);
    const char* buf = lds + (t & 1) * 32768;
    bf16x8 wf[4][2], xf[4][2];
    #pragma unroll
    for (int mi = 0; mi < 4; mi++)
      #pragma unroll
      for (int ks = 0; ks < 2; ks++) {
        int r = eq + mi * 16 + lc;
        wf[mi][ks] = *(const bf16x8*)(buf + r * 128 + (((ks * 4 + grp) ^ (r & 7)) * 16));
      }
    #pragma unroll
    for (int ni = 0; ni < 4; ni++)
      #pragma unroll
      for (int ks = 0; ks < 2; ks++) {
        int r = nq + ni * 16 + lc;
        xf[ni][ks] = *(const bf16x8*)(buf + 16384 + r * 128 + (((ks * 4 + grp) ^ (r & 7)) * 16));
      }
    #pragma unroll
    for (int mi = 0; mi < 4; mi++)
      #pragma unroll
      for (int ni = 0; ni < 4; ni++) {
        acc[mi][ni] = MFMA(wf[mi][0], xf[ni][0], acc[mi][ni]);
        acc[mi][ni] = MFMA(wf[mi][1], xf[ni][1], acc[mi][ni]);
      }
  }
  short* Vbp = V + (size_t)b * NC * NN;
  #pragma unroll
  for (int mi = 0; mi < 4; mi++)
    #pragma unroll
    for (int j = 0; j < 4; j++) {
      int e = e0 + eq + mi * 16 + grp * 4 + j;
      float bb = bv[e];
      #pragma unroll
      for (int ni = 0; ni < 4; ni++) {
        int nu = (ni & 1) * 16 + lc;
        int kap = ((nu >> 2) & 3) * 8 + ((nu >> 4) & 1) * 4 + (nu & 3);
        int n = n0 + nq + (ni >> 1) * 32 + kap;
        Vbp[(size_t)e * NN + n] = f2bf(acc[mi][ni][j] + bb);
      }
    }
}

// ---------------- kernel 5: softmax stats, n-split partials ----------------
__global__ __launch_bounds__(256, 2) void attn_stats(const short* Q, const short* K,
                                                     float* Mp, float* Lp) {
  __shared__ char lds[16384];
  int b = blockIdx.y, nh = blockIdx.z;
  int tid = threadIdx.x, wave = tid >> 6, lane = tid & 63;
  int lc = lane & 15, grp = lane >> 4;
  int m0 = blockIdx.x * 128 + wave * 32;
  const short* Qb = Q + (size_t)b * NN * ND;
  const char* Kg = (const char*)(K + (size_t)b * NN * ND);

  int kR[2], kC[2];
  #pragma unroll
  for (int i = 0; i < 2; i++) {
    int A = (wave * 2 + i) * 1024 + lane * 16;
    kR[i] = A >> 7;
    kC[i] = ((A >> 4) & 7) ^ (kR[i] & 7);
  }
  auto stageK = [&](char* base0, int n0) {
    #pragma unroll
    for (int i = 0; i < 2; i++)
      gld16(base0 + (wave * 2 + i) * 1024,
            Kg + (size_t)(n0 + kR[i]) * 128 + kC[i] * 16);
  };

  bf16x8 qf[2][2];
  #pragma unroll
  for (int mi = 0; mi < 2; mi++)
    #pragma unroll
    for (int kk = 0; kk < 2; kk++)
      qf[mi][kk] = *(const bf16x8*)(Qb + (size_t)(m0 + mi * 16 + lc) * ND + kk * 32 + grp * 8);

  float rmax[2][4], rsum[2][4];
  #pragma unroll
  for (int mi = 0; mi < 2; mi++)
    #pragma unroll
    for (int j = 0; j < 4; j++) { rmax[mi][j] = -1e30f; rsum[mi][j] = 0.f; }

  stageK(lds, nh * 2048);
  __syncthreads();
  int cur = 0;
  for (int tt = 0; tt < 32; tt++) {
    int t = nh * 32 + tt;
    if (tt + 1 < 32) stageK(lds + (cur ^ 1) * 8192, (t + 1) * 64);
    const char* Kb_l = lds + cur * 8192;
    f32x4 s[2][4] = {};
    #pragma unroll
    for (int ni = 0; ni < 4; ni++) {
      int row = ni * 16 + lc;
      bf16x8 kf0 = *(const bf16x8*)(Kb_l + row * 128 + ((grp ^ (row & 7)) * 16));
      bf16x8 kf1 = *(const bf16x8*)(Kb_l + row * 128 + (((grp + 4) ^ (row & 7)) * 16));
      #pragma unroll
      for (int mi = 0; mi < 2; mi++) {
        s[mi][ni] = MFMA(qf[mi][0], kf0, s[mi][ni]);
        s[mi][ni] = MFMA(qf[mi][1], kf1, s[mi][ni]);
      }
    }
    #pragma unroll
    for (int mi = 0; mi < 2; mi++)
      #pragma unroll
      for (int j = 0; j < 4; j++) {
        float a0 = s[mi][0][j], a1 = s[mi][1][j], a2 = s[mi][2][j], a3 = s[mi][3][j];
        float m4 = fmaxf(fmaxf(a0, a1), fmaxf(a2, a3));
        float nm = fmaxf(rmax[mi][j], m4);
        rsum[mi][j] = rsum[mi][j] * exp2f(rmax[mi][j] - nm)
                    + exp2f(a0 - nm) + exp2f(a1 - nm) + exp2f(a2 - nm) + exp2f(a3 - nm);
        rmax[mi][j] = nm;
      }
    __syncthreads();
    cur ^= 1;
  }
  #pragma unroll
  for (int mi = 0; mi < 2; mi++)
    #pragma unroll
    for (int j = 0; j < 4; j++) {
      float gm = rmax[mi][j];
      for (int o = 1; o < 16; o <<= 1) gm = fmaxf(gm, __shfl_xor(gm, o));
      float ps = rsum[mi][j] * exp2f(rmax[mi][j] - gm);
      for (int o = 1; o < 16; o <<= 1) ps += __shfl_xor(ps, o);
      if (lc == 0) {
        int m = m0 + mi * 16 + grp * 4 + j;
        Mp[((size_t)nh * NB + b) * NN + m] = gm;
        Lp[((size_t)nh * NB + b) * NN + m] = ps;
      }
    }
}

__global__ void stats_combine(const float* Mp, const float* Lp, float* Mrow, float* Lrow) {
  int i = blockIdx.x * 256 + threadIdx.x;
  if (i >= NB * NN) return;
  float m0 = Mp[i], m1 = Mp[NB * NN + i];
  float M = fmaxf(m0, m1);
  float L = Lp[i] * exp2f(m0 - M) + Lp[NB * NN + i] * exp2f(m1 - M);
  Mrow[i] = M; Lrow[i] = L;
}

// ---------------- kernel 6: out = gamma * (softmax(QK^T) @ V^T) + x ----------
// Block 128m x 128e, 2 waves (wave = 64m x 128e). Swapped QK^T (S^T = K x Q):
// lane's P row is m = 16mi + lc, P stays in registers; pi-permuted V makes the
// PV A-fragment the lane's own values (no shuffle, no P LDS). K/V dbuf in LDS.
__global__ __launch_bounds__(128, 1) void attn_out_kernel(
    const short* Q, const short* K, const short* Vp,
    const float* Mrow, const float* Lrow, const float* x,
    const float* gamma, float* out) {
  __shared__ char lds[49152];   // K dbuf 2x8K @0, V dbuf 2x16K @16384
  int b  = blockIdx.z;
  int e0 = blockIdx.y * 128;
  int m0 = blockIdx.x * 128;
  int tid = threadIdx.x, wv = tid >> 6, lane = tid & 63;
  int lc = lane & 15, grp = lane >> 4;
  int mw = m0 + wv * 64;

  const short* Qb = Q + (size_t)b * NN * ND;
  const char* Kg = (const char*)(K + (size_t)b * NN * ND);
  const char* Vg = (const char*)(Vp + (size_t)b * NC * NN);

  // staging decomposition: 128 threads, 16B chunks; linear LDS dest,
  // inverse-swizzled global source (granule g at row r holds global g^(r&7)).
  int kR[4], kC[4], vR[8], vC[8];
  #pragma unroll
  for (int i = 0; i < 4; i++) {
    int ch = i * 128 + tid;
    kR[i] = ch >> 3; kC[i] = (ch & 7) ^ (kR[i] & 7);
  }
  #pragma unroll
  for (int i = 0; i < 8; i++) {
    int ch = i * 128 + tid;
    vR[i] = ch >> 3; vC[i] = (ch & 7) ^ (vR[i] & 7);
  }
  auto stageK = [&](char* dst, int n0) {
    #pragma unroll
    for (int i = 0; i < 4; i++)
      gld16(dst + (i * 128 + tid) * 16, Kg + (size_t)(n0 + kR[i]) * 128 + kC[i] * 16);
  };
  auto stageV = [&](char* dst, int n0) {
    #pragma unroll
    for (int i = 0; i < 8; i++)
      gld16(dst + (i * 128 + tid) * 16, Vg + (size_t)(e0 + vR[i]) * 8192 + (size_t)n0 * 2 + vC[i] * 16);
  };

  bf16x8 qf[4][2];
  #pragma unroll
  for (int mi = 0; mi < 4; mi++)
    #pragma unroll
    for (int dk = 0; dk < 2; dk++)
      qf[mi][dk] = *(const bf16x8*)(Qb + (size_t)(mw + mi * 16 + lc) * ND + dk * 32 + grp * 8);
  float Mr[4];
  #pragma unroll
  for (int mi = 0; mi < 4; mi++)
    Mr[mi] = Mrow[(size_t)b * NN + mw + mi * 16 + lc];

  f32x4 acc[4][8] = {};   // [mi][ei]: D[m=16mi span][e=16ei span]

  stageK(lds, 0);
  stageV(lds + 16384, 0);
  __syncthreads();
  int cur = 0;
  for (int t = 0; t < 64; t++) {
    if (t < 63) {
      stageK(lds + (cur ^ 1) * 8192, (t + 1) * 64);
      stageV(lds + 16384 + (cur ^ 1) * 16384, (t + 1) * 64);
    }
    const char* Kl = lds + cur * 8192;
    const char* Vl = lds + 16384 + cur * 16384;

    // K fragments (A-operand of S^T): rows n = 16ni + lc
    bf16x8 kf[4][2];
    #pragma unroll
    for (int ni = 0; ni < 4; ni++)
      #pragma unroll
      for (int dk = 0; dk < 2; dk++) {
        int row = ni * 16 + lc;
        kf[ni][dk] = *(const bf16x8*)(Kl + row * 128 + (((dk * 4 + grp) ^ (row & 7)) * 16));
      }

    // S^T = K Q per mi; P = exp2(S - M) packed straight into PV A-fragments
    bf16x8 pa[4][2];
    #pragma unroll
    for (int mi = 0; mi < 4; mi++) {
      f32x4 s[4];
      #pragma unroll
      for (int ni = 0; ni < 4; ni++) {
        f32x4 z = {0.f, 0.f, 0.f, 0.f};
        z = MFMA(kf[ni][0], qf[mi][0], z);
        z = MFMA(kf[ni][1], qf[mi][1], z);
        s[ni] = z;
      }
      float M = Mr[mi];
      union { unsigned u[8]; bf16x8 v[2]; } pk;
      #pragma unroll
      for (int ni = 0; ni < 4; ni++) {
        float p0 = exp2f(s[ni][0] - M);
        float p1 = exp2f(s[ni][1] - M);
        float p2 = exp2f(s[ni][2] - M);
        float p3 = exp2f(s[ni][3] - M);
        pk.u[ni * 2]     = cvt_pk_bf16(p0, p1);
        pk.u[ni * 2 + 1] = cvt_pk_bf16(p2, p3);
      }
      pa[mi][0] = pk.v[0];
      pa[mi][1] = pk.v[1];
    }

    // O += P V^T  (V pi-permuted so B-fragment is a plain b128)
    #pragma unroll
    for (int ei = 0; ei < 8; ei++) {
      int row = ei * 16 + lc;
      bf16x8 v0 = *(const bf16x8*)(Vl + row * 128 + ((grp ^ (row & 7)) * 16));
      bf16x8 v1 = *(const bf16x8*)(Vl + row * 128 + (((4 + grp) ^ (row & 7)) * 16));
      #pragma unroll
      for (int mi = 0; mi < 4; mi++) {
        acc[mi][ei] = MFMA(pa[mi][0], v0, acc[mi][ei]);
        acc[mi][ei] = MFMA(pa[mi][1], v1, acc[mi][ei]);
      }
    }
    __syncthreads();
    cur ^= 1;
  }

  // epilogue: out[e][m] = gamma * acc / L + x
  float Li[4][4];
  #pragma unroll
  for (int mi = 0; mi < 4; mi++)
    #pragma unroll
    for (int j = 0; j < 4; j++)
      Li[mi][j] = 1.0f / Lrow[(size_t)b * NN + mw + mi * 16 + grp * 4 + j];
  const float* xb = x + (size_t)b * NC * NN;
  float* ob = out + (size_t)b * NC * NN;
  float g = gamma[0];
  #pragma unroll
  for (int mi = 0; mi < 4; mi++)
    #pragma unroll
    for (int ei = 0; ei < 8; ei++) {
      int e = e0 + ei * 16 + lc;
      int mbase = mw + mi * 16 + grp * 4;
      f32x4 xv = *(const f32x4*)(xb + (size_t)e * NN + mbase);
      f32x4 r;
      #pragma unroll
      for (int j = 0; j < 4; j++)
        r[j] = g * (acc[mi][ei][j] * Li[mi][j]) + xv[j];
      *(f32x4*)(ob + (size_t)e * NN + mbase) = r;
    }
}

extern "C" void kernel_launch(void* const* d_in, const int* in_sizes, int n_in,
                              void* d_out, int out_size, void* d_ws, size_t ws_size,
                              hipStream_t stream) {
  const float* x     = (const float*)d_in[0];
  const float* Wq    = (const float*)d_in[1];
  const float* bq    = (const float*)d_in[2];
  const float* Wk    = (const float*)d_in[3];
  const float* bk    = (const float*)d_in[4];
  const float* Wv    = (const float*)d_in[5];
  const float* bv    = (const float*)d_in[6];
  const float* gamma = (const float*)d_in[7];
  float* out = (float*)d_out;

  char* ws = (char*)d_ws;
  size_t off = 0;
  auto alloc = [&](size_t bytes) {
    void* p = ws + off;
    off = (off + bytes + 255) & ~(size_t)255;
    return p;
  };
  short* xT   = (short*)alloc((size_t)NB * NN * NC * 2);   // 16 MB
  short* Wqb  = (short*)alloc((size_t)ND * NC * 2);
  short* Wkb  = (short*)alloc((size_t)ND * NC * 2);
  short* Wvb  = (short*)alloc((size_t)NC * NC * 2);
  short* Qb   = (short*)alloc((size_t)NB * NN * ND * 2);   // 2 MB
  short* Kb   = (short*)alloc((size_t)NB * NN * ND * 2);   // 2 MB
  short* Vb   = (short*)alloc((size_t)NB * NC * NN * 2);   // 16 MB (pi-permuted)
  float* Mrow = (float*)alloc((size_t)NB * NN * 4);
  float* Lrow = (float*)alloc((size_t)NB * NN * 4);
  float* Mp   = (float*)alloc((size_t)2 * NB * NN * 4);
  float* Lp   = (float*)alloc((size_t)2 * NB * NN * 4);

  cast_w<<<dim3(1024), dim3(256), 0, stream>>>(Wq, Wk, Wv, Wqb, Wkb, Wvb);
  transpose_x<<<dim3(NN / 64, NC / 32, NB), dim3(256), 0, stream>>>(x, xT);
  proj_qk<<<dim3(NN / 64, NB), dim3(256), 0, stream>>>(xT, Wqb, Wkb, bq, bk, Qb, Kb);
  proj_v<<<dim3(NN / 128, NC / 128, NB), dim3(256), 0, stream>>>(xT, Wvb, bv, Vb);
  attn_stats<<<dim3(NN / 128, NB, 2), dim3(256), 0, stream>>>(Qb, Kb, Mp, Lp);
  stats_combine<<<dim3(NB * NN / 256), dim3(256), 0, stream>>>(Mp, Lp, Mrow, Lrow);
  attn_out_kernel<<<dim3(NN / 128, NC / 128, NB), dim3(128), 0, stream>>>(
      Qb, Kb, Vb, Mrow, Lrow, x, gamma, out);
}

// Round 5
// 212.555 us; speedup vs baseline: 2.5610x; 1.1759x over previous
//
#include <hip/hip_runtime.h>
#include <math.h>

using bf16x8 = __attribute__((ext_vector_type(8))) short;
using f32x4  = __attribute__((ext_vector_type(4))) float;

#define MFMA(a,b,c) __builtin_amdgcn_mfma_f32_16x16x32_bf16((a),(b),(c),0,0,0)

static constexpr int NB = 4, NC = 512, NN = 4096, ND = 64;
static constexpr float LOG2E = 1.4426950408889634f;

__device__ __forceinline__ short f2bf(float f) {
  union { float f; unsigned u; } v; v.f = f;
  unsigned r = v.u + 0x7FFFu + ((v.u >> 16) & 1u);
  return (short)(r >> 16);
}

__device__ __forceinline__ unsigned cvt_pk_bf16(float a, float b) {
  unsigned r;
  asm("v_cvt_pk_bf16_f32 %0, %1, %2" : "=v"(r) : "v"(a), "v"(b));
  return r;
}

__device__ __forceinline__ void gld16(void* lds, const void* g) {
  __builtin_amdgcn_global_load_lds(
      (const __attribute__((address_space(1))) unsigned*)g,
      (__attribute__((address_space(3))) unsigned*)lds, 16, 0, 0);
}

// ---------------- kernel 1: cast weights to bf16 ----------------
__global__ void cast_w(const float* Wq, const float* Wk, const float* Wv,
                       short* Wqb, short* Wkb, short* Wvb) {
  int i = blockIdx.x * 256 + threadIdx.x;
  if (i < ND * NC) { Wqb[i] = f2bf(Wq[i]); Wkb[i] = f2bf(Wk[i]); }
  if (i < NC * NC) { Wvb[i] = f2bf(Wv[i]); }
}

// ---------------- kernel 2: x (B,C,N) f32 -> xT (B,N,C) bf16 (LDS-free) ------
__global__ __launch_bounds__(256) void transpose_x(const float* x, short* xT) {
  int b = blockIdx.z, c0 = blockIdx.y * 32, n0 = blockIdx.x * 64;
  int tid = threadIdx.x;
  int n = n0 + (tid >> 2);
  int c = c0 + (tid & 3) * 8;
  const float* xb = x + (size_t)b * NC * NN;
  bf16x8 v;
  #pragma unroll
  for (int i = 0; i < 8; i++) v[i] = f2bf(xb[(size_t)(c + i) * NN + n]);
  *(bf16x8*)(xT + ((size_t)b * NN + n) * NC + c) = v;
}

// ---------------- kernel 3: Q,K projections -> (B,N,64) bf16 ----------------
// Q pre-scaled by log2(e): downstream softmax uses exp2.
__global__ __launch_bounds__(256) void proj_qk(const short* xT, const short* Wqb, const short* Wkb,
                        const float* bq, const float* bk, short* Q, short* K) {
  int b = blockIdx.y;
  int wave = threadIdx.x >> 6, lane = threadIdx.x & 63;
  int lc = lane & 15, grp = lane >> 4;
  int n0 = blockIdx.x * 64 + wave * 16;
  const short* xTb = xT + ((size_t)b * NN + n0) * NC;
  f32x4 accq[4] = {}, acck[4] = {};
  for (int c0 = 0; c0 < NC; c0 += 32) {
    bf16x8 a = *(const bf16x8*)(xTb + (size_t)lc * NC + c0 + grp * 8);
    #pragma unroll
    for (int di = 0; di < 4; di++) {
      bf16x8 wq = *(const bf16x8*)(Wqb + (size_t)(di * 16 + lc) * NC + c0 + grp * 8);
      bf16x8 wk = *(const bf16x8*)(Wkb + (size_t)(di * 16 + lc) * NC + c0 + grp * 8);
      accq[di] = MFMA(a, wq, accq[di]);
      acck[di] = MFMA(a, wk, acck[di]);
    }
  }
  short* Qb = Q + (size_t)b * NN * ND;
  short* Kb = K + (size_t)b * NN * ND;
  #pragma unroll
  for (int di = 0; di < 4; di++)
    #pragma unroll
    for (int j = 0; j < 4; j++) {
      int n = n0 + grp * 4 + j;
      int d = di * 16 + lc;
      Qb[(size_t)n * ND + d] = f2bf((accq[di][j] + bq[d]) * LOG2E);
      Kb[(size_t)n * ND + d] = f2bf(acck[di][j] + bk[d]);
    }
}

// ---------------- kernel 4: V projection -> (B,C,N) bf16, pi-permuted cols ----
// Vp[e][32t + kap] = V[e][32t + pi(kap)], pi(k)=16*((k>>2)&1)+4*(k>>3)+(k&3).
// Inverse: value at n (nu = n&31) goes to kap = 8*((nu>>2)&3)+4*((nu>>4)&1)+(nu&3).
__global__ __launch_bounds__(256, 2) void proj_v(const short* xT, const short* Wvb,
                                                 const float* bv, short* V) {
  __shared__ char lds[65536];   // dbuf: [Wv 16K | xT 16K] x2
  int b = blockIdx.z;
  int tid = threadIdx.x, wv = tid >> 6, lane = tid & 63;
  int lc = lane & 15, grp = lane >> 4;
  int e0 = blockIdx.y * 128;
  int n0 = blockIdx.x * 128;
  const char* Wg = (const char*)Wvb;
  const char* Xg = (const char*)(xT + (size_t)b * NN * NC);
  int eq = (wv >> 1) * 64, nq = (wv & 1) * 64;

  auto stage = [&](int t) {
    char* buf = lds + (t & 1) * 32768;
    int c0 = t * 64;
    #pragma unroll
    for (int i = 0; i < 4; i++) {
      int r = wv * 32 + i * 8 + (lane >> 3), g = lane & 7;
      gld16(buf + wv * 4096 + i * 1024 + lane * 16,
            Wg + (size_t)(e0 + r) * 1024 + (size_t)c0 * 2 + ((g ^ (r & 7)) * 16));
    }
    #pragma unroll
    for (int i = 0; i < 4; i++) {
      int r = wv * 32 + i * 8 + (lane >> 3), g = lane & 7;
      gld16(buf + 16384 + wv * 4096 + i * 1024 + lane * 16,
            Xg + (size_t)(n0 + r) * 1024 + (size_t)c0 * 2 + ((g ^ (r & 7)) * 16));
    }
  };

  f32x4 acc[4][4] = {};
  stage(0);
  for (int t = 0; t < 8; t++) {
    asm volatile("s_waitcnt vmcnt(0)" ::: "memory");
    __builtin_amdgcn_sched_barrier(0);
    __builtin_amdgcn_s_barrier();
    if (t < 7) stage(t + 1);
    const char* buf = lds + (t & 1) * 32768;
    bf16x8 wf[4][2], xf[4][2];
    #pragma unroll
    for (int mi = 0; mi < 4; mi++)
      #pragma unroll
      for (int ks = 0; ks < 2; ks++) {
        int r = eq + mi * 16 + lc;
        wf[mi][ks] = *(const bf16x8*)(buf + r * 128 + (((ks * 4 + grp) ^ (r & 7)) * 16));
      }
    #pragma unroll
    for (int ni = 0; ni < 4; ni++)
      #pragma unroll
      for (int ks = 0; ks < 2; ks++) {
        int r = nq + ni * 16 + lc;
        xf[ni][ks] = *(const bf16x8*)(buf + 16384 + r * 128 + (((ks * 4 + grp) ^ (r & 7)) * 16));
      }
    #pragma unroll
    for (int mi = 0; mi < 4; mi++)
      #pragma unroll
      for (int ni = 0; ni < 4; ni++) {
        acc[mi][ni] = MFMA(wf[mi][0], xf[ni][0], acc[mi][ni]);
        acc[mi][ni] = MFMA(wf[mi][1], xf[ni][1], acc[mi][ni]);
      }
  }
  short* Vbp = V + (size_t)b * NC * NN;
  #pragma unroll
  for (int mi = 0; mi < 4; mi++)
    #pragma unroll
    for (int j = 0; j < 4; j++) {
      int e = e0 + eq + mi * 16 + grp * 4 + j;
      float bb = bv[e];
      #pragma unroll
      for (int ni = 0; ni < 4; ni++) {
        int nu = (ni & 1) * 16 + lc;
        int kap = ((nu >> 2) & 3) * 8 + ((nu >> 4) & 1) * 4 + (nu & 3);
        int n = n0 + nq + (ni >> 1) * 32 + kap;
        Vbp[(size_t)e * NN + n] = f2bf(acc[mi][ni][j] + bb);
      }
    }
}

// ---------------- kernel 5: softmax stats, n-split partials ----------------
__global__ __launch_bounds__(256, 2) void attn_stats(const short* Q, const short* K,
                                                     float* Mp, float* Lp) {
  __shared__ char lds[16384];
  int b = blockIdx.y, nh = blockIdx.z;
  int tid = threadIdx.x, wave = tid >> 6, lane = tid & 63;
  int lc = lane & 15, grp = lane >> 4;
  int m0 = blockIdx.x * 128 + wave * 32;
  const short* Qb = Q + (size_t)b * NN * ND;
  const char* Kg = (const char*)(K + (size_t)b * NN * ND);

  int kR[2], kC[2];
  #pragma unroll
  for (int i = 0; i < 2; i++) {
    int A = (wave * 2 + i) * 1024 + lane * 16;
    kR[i] = A >> 7;
    kC[i] = ((A >> 4) & 7) ^ (kR[i] & 7);
  }
  auto stageK = [&](char* base0, int n0) {
    #pragma unroll
    for (int i = 0; i < 2; i++)
      gld16(base0 + (wave * 2 + i) * 1024,
            Kg + (size_t)(n0 + kR[i]) * 128 + kC[i] * 16);
  };

  bf16x8 qf[2][2];
  #pragma unroll
  for (int mi = 0; mi < 2; mi++)
    #pragma unroll
    for (int kk = 0; kk < 2; kk++)
      qf[mi][kk] = *(const bf16x8*)(Qb + (size_t)(m0 + mi * 16 + lc) * ND + kk * 32 + grp * 8);

  float rmax[2][4], rsum[2][4];
  #pragma unroll
  for (int mi = 0; mi < 2; mi++)
    #pragma unroll
    for (int j = 0; j < 4; j++) { rmax[mi][j] = -1e30f; rsum[mi][j] = 0.f; }

  stageK(lds, nh * 2048);
  __syncthreads();
  int cur = 0;
  for (int tt = 0; tt < 32; tt++) {
    int t = nh * 32 + tt;
    if (tt + 1 < 32) stageK(lds + (cur ^ 1) * 8192, (t + 1) * 64);
    const char* Kb_l = lds + cur * 8192;
    f32x4 s[2][4] = {};
    #pragma unroll
    for (int ni = 0; ni < 4; ni++) {
      int row = ni * 16 + lc;
      bf16x8 kf0 = *(const bf16x8*)(Kb_l + row * 128 + ((grp ^ (row & 7)) * 16));
      bf16x8 kf1 = *(const bf16x8*)(Kb_l + row * 128 + (((grp + 4) ^ (row & 7)) * 16));
      #pragma unroll
      for (int mi = 0; mi < 2; mi++) {
        s[mi][ni] = MFMA(qf[mi][0], kf0, s[mi][ni]);
        s[mi][ni] = MFMA(qf[mi][1], kf1, s[mi][ni]);
      }
    }
    #pragma unroll
    for (int mi = 0; mi < 2; mi++)
      #pragma unroll
      for (int j = 0; j < 4; j++) {
        float a0 = s[mi][0][j], a1 = s[mi][1][j], a2 = s[mi][2][j], a3 = s[mi][3][j];
        float m4 = fmaxf(fmaxf(a0, a1), fmaxf(a2, a3));
        float nm = fmaxf(rmax[mi][j], m4);
        rsum[mi][j] = rsum[mi][j] * exp2f(rmax[mi][j] - nm)
                    + exp2f(a0 - nm) + exp2f(a1 - nm) + exp2f(a2 - nm) + exp2f(a3 - nm);
        rmax[mi][j] = nm;
      }
    __syncthreads();
    cur ^= 1;
  }
  #pragma unroll
  for (int mi = 0; mi < 2; mi++)
    #pragma unroll
    for (int j = 0; j < 4; j++) {
      float gm = rmax[mi][j];
      for (int o = 1; o < 16; o <<= 1) gm = fmaxf(gm, __shfl_xor(gm, o));
      float ps = rsum[mi][j] * exp2f(rmax[mi][j] - gm);
      for (int o = 1; o < 16; o <<= 1) ps += __shfl_xor(ps, o);
      if (lc == 0) {
        int m = m0 + mi * 16 + grp * 4 + j;
        Mp[((size_t)nh * NB + b) * NN + m] = gm;
        Lp[((size_t)nh * NB + b) * NN + m] = ps;
      }
    }
}

__global__ void stats_combine(const float* Mp, const float* Lp, float* Mrow, float* Lrow) {
  int i = blockIdx.x * 256 + threadIdx.x;
  if (i >= NB * NN) return;
  float m0 = Mp[i], m1 = Mp[NB * NN + i];
  float M = fmaxf(m0, m1);
  float L = Lp[i] * exp2f(m0 - M) + Lp[NB * NN + i] * exp2f(m1 - M);
  Mrow[i] = M; Lrow[i] = L;
}

// ---------------- kernel 6: out = gamma * (softmax(QK^T) @ V^T) + x ----------
// r2 skeleton (256 thr, 4 waves, 128m x 128e block, dbuf + 1 syncthreads/step)
// + swapped QK^T register-P (no P LDS) + pi-permuted V. Wave = 32m x 128e.
// LDS 48K -> 3 blocks/CU.
__global__ __launch_bounds__(256, 3) void attn_out_kernel(
    const short* Q, const short* K, const short* Vp,
    const float* Mrow, const float* Lrow, const float* x,
    const float* gamma, float* out) {
  __shared__ char lds[49152];   // K dbuf 2x8K @0, V dbuf 2x16K @16384
  int b  = blockIdx.z;
  int e0 = blockIdx.y * 128;
  int m0 = blockIdx.x * 128;
  int tid = threadIdx.x, wv = tid >> 6, lane = tid & 63;
  int lc = lane & 15, grp = lane >> 4;
  int mw = m0 + wv * 32;

  const short* Qb = Q + (size_t)b * NN * ND;
  const char* Kg = (const char*)(K + (size_t)b * NN * ND);
  const char* Vg = (const char*)(Vp + (size_t)b * NC * NN);

  // staging: 256 threads x 16B chunks; linear LDS dest, inverse-swizzled source
  int kR[2], kC[2], vR[4], vC[4];
  #pragma unroll
  for (int i = 0; i < 2; i++) {
    int ch = i * 256 + tid;
    kR[i] = ch >> 3; kC[i] = (ch & 7) ^ (kR[i] & 7);
  }
  #pragma unroll
  for (int i = 0; i < 4; i++) {
    int ch = i * 256 + tid;
    vR[i] = ch >> 3; vC[i] = (ch & 7) ^ (vR[i] & 7);
  }
  auto stageK = [&](char* dst, int n0) {
    #pragma unroll
    for (int i = 0; i < 2; i++)
      gld16(dst + (i * 256 + tid) * 16, Kg + (size_t)(n0 + kR[i]) * 128 + kC[i] * 16);
  };
  auto stageV = [&](char* dst, int n0) {
    #pragma unroll
    for (int i = 0; i < 4; i++)
      gld16(dst + (i * 256 + tid) * 16,
            Vg + (size_t)(e0 + vR[i]) * 8192 + (size_t)n0 * 2 + vC[i] * 16);
  };

  bf16x8 qf[2][2];
  #pragma unroll
  for (int mi = 0; mi < 2; mi++)
    #pragma unroll
    for (int dk = 0; dk < 2; dk++)
      qf[mi][dk] = *(const bf16x8*)(Qb + (size_t)(mw + mi * 16 + lc) * ND + dk * 32 + grp * 8);
  float Mr[2];
  #pragma unroll
  for (int mi = 0; mi < 2; mi++)
    Mr[mi] = Mrow[(size_t)b * NN + mw + mi * 16 + lc];

  f32x4 acc[2][8] = {};   // [mi][ei]

  stageK(lds, 0);
  stageV(lds + 16384, 0);
  __syncthreads();
  int cur = 0;
  for (int t = 0; t < 64; t++) {
    if (t < 63) {
      stageK(lds + (cur ^ 1) * 8192, (t + 1) * 64);
      stageV(lds + 16384 + (cur ^ 1) * 16384, (t + 1) * 64);
    }
    const char* Kl = lds + cur * 8192;
    const char* Vl = lds + 16384 + cur * 16384;

    // K fragments (A-operand of S^T): rows n = 16ni + lc
    bf16x8 kf[4][2];
    #pragma unroll
    for (int ni = 0; ni < 4; ni++)
      #pragma unroll
      for (int dk = 0; dk < 2; dk++) {
        int row = ni * 16 + lc;
        kf[ni][dk] = *(const bf16x8*)(Kl + row * 128 + (((dk * 4 + grp) ^ (row & 7)) * 16));
      }

    // S^T = K Q; P = exp2(S - M) packed straight into PV A-fragments
    bf16x8 pa[2][2];
    #pragma unroll
    for (int mi = 0; mi < 2; mi++) {
      f32x4 s[4];
      #pragma unroll
      for (int ni = 0; ni < 4; ni++) {
        f32x4 z = {0.f, 0.f, 0.f, 0.f};
        z = MFMA(kf[ni][0], qf[mi][0], z);
        z = MFMA(kf[ni][1], qf[mi][1], z);
        s[ni] = z;
      }
      float M = Mr[mi];
      union { unsigned u[8]; bf16x8 v[2]; } pk;
      #pragma unroll
      for (int ni = 0; ni < 4; ni++) {
        float p0 = exp2f(s[ni][0] - M);
        float p1 = exp2f(s[ni][1] - M);
        float p2 = exp2f(s[ni][2] - M);
        float p3 = exp2f(s[ni][3] - M);
        pk.u[ni * 2]     = cvt_pk_bf16(p0, p1);
        pk.u[ni * 2 + 1] = cvt_pk_bf16(p2, p3);
      }
      pa[mi][0] = pk.v[0];
      pa[mi][1] = pk.v[1];
    }

    // O += P V^T (pi-permuted V: B-fragment is a plain b128)
    #pragma unroll
    for (int ei = 0; ei < 8; ei++) {
      int row = ei * 16 + lc;
      bf16x8 v0 = *(const bf16x8*)(Vl + row * 128 + ((grp ^ (row & 7)) * 16));
      bf16x8 v1 = *(const bf16x8*)(Vl + row * 128 + (((4 + grp) ^ (row & 7)) * 16));
      #pragma unroll
      for (int mi = 0; mi < 2; mi++) {
        acc[mi][ei] = MFMA(pa[mi][0], v0, acc[mi][ei]);
        acc[mi][ei] = MFMA(pa[mi][1], v1, acc[mi][ei]);
      }
    }
    __syncthreads();
    cur ^= 1;
  }

  // epilogue: out[e][m] = gamma * acc / L + x
  float Li[2][4];
  #pragma unroll
  for (int mi = 0; mi < 2; mi++)
    #pragma unroll
    for (int j = 0; j < 4; j++)
      Li[mi][j] = 1.0f / Lrow[(size_t)b * NN + mw + mi * 16 + grp * 4 + j];
  const float* xb = x + (size_t)b * NC * NN;
  float* ob = out + (size_t)b * NC * NN;
  float g = gamma[0];
  #pragma unroll
  for (int mi = 0; mi < 2; mi++)
    #pragma unroll
    for (int ei = 0; ei < 8; ei++) {
      int e = e0 + ei * 16 + lc;
      int mbase = mw + mi * 16 + grp * 4;
      f32x4 xv = *(const f32x4*)(xb + (size_t)e * NN + mbase);
      f32x4 r;
      #pragma unroll
      for (int j = 0; j < 4; j++)
        r[j] = g * (acc[mi][ei][j] * Li[mi][j]) + xv[j];
      *(f32x4*)(ob + (size_t)e * NN + mbase) = r;
    }
}

extern "C" void kernel_launch(void* const* d_in, const int* in_sizes, int n_in,
                              void* d_out, int out_size, void* d_ws, size_t ws_size,
                              hipStream_t stream) {
  const float* x     = (const float*)d_in[0];
  const float* Wq    = (const float*)d_in[1];
  const float* bq    = (const float*)d_in[2];
  const float* Wk    = (const float*)d_in[3];
  const float* bk    = (const float*)d_in[4];
  const float* Wv    = (const float*)d_in[5];
  const float* bv    = (const float*)d_in[6];
  const float* gamma = (const float*)d_in[7];
  float* out = (float*)d_out;

  char* ws = (char*)d_ws;
  size_t off = 0;
  auto alloc = [&](size_t bytes) {
    void* p = ws + off;
    off = (off + bytes + 255) & ~(size_t)255;
    return p;
  };
  short* xT   = (short*)alloc((size_t)NB * NN * NC * 2);   // 16 MB
  short* Wqb  = (short*)alloc((size_t)ND * NC * 2);
  short* Wkb  = (short*)alloc((size_t)ND * NC * 2);
  short* Wvb  = (short*)alloc((size_t)NC * NC * 2);
  short* Qb   = (short*)alloc((size_t)NB * NN * ND * 2);   // 2 MB
  short* Kb   = (short*)alloc((size_t)NB * NN * ND * 2);   // 2 MB
  short* Vb   = (short*)alloc((size_t)NB * NC * NN * 2);   // 16 MB (pi-permuted)
  float* Mrow = (float*)alloc((size_t)NB * NN * 4);
  float* Lrow = (float*)alloc((size_t)NB * NN * 4);
  float* Mp   = (float*)alloc((size_t)2 * NB * NN * 4);
  float* Lp   = (float*)alloc((size_t)2 * NB * NN * 4);

  cast_w<<<dim3(1024), dim3(256), 0, stream>>>(Wq, Wk, Wv, Wqb, Wkb, Wvb);
  transpose_x<<<dim3(NN / 64, NC / 32, NB), dim3(256), 0, stream>>>(x, xT);
  proj_qk<<<dim3(NN / 64, NB), dim3(256), 0, stream>>>(xT, Wqb, Wkb, bq, bk, Qb, Kb);
  proj_v<<<dim3(NN / 128, NC / 128, NB), dim3(256), 0, stream>>>(xT, Wvb, bv, Vb);
  attn_stats<<<dim3(NN / 128, NB, 2), dim3(256), 0, stream>>>(Qb, Kb, Mp, Lp);
  stats_combine<<<dim3(NB * NN / 256), dim3(256), 0, stream>>>(Mp, Lp, Mrow, Lrow);
  attn_out_kernel<<<dim3(NN / 128, NC / 128, NB), dim3(256), 0, stream>>>(
      Qb, Kb, Vb, Mrow, Lrow, x, gamma, out);
}

// Round 6
// 183.226 us; speedup vs baseline: 2.9709x; 1.1601x over previous
//
#include <hip/hip_runtime.h>
#include <math.h>

using bf16x8 = __attribute__((ext_vector_type(8))) short;
using f32x4  = __attribute__((ext_vector_type(4))) float;

#define MFMA(a,b,c) __builtin_amdgcn_mfma_f32_16x16x32_bf16((a),(b),(c),0,0,0)

static constexpr int NB = 4, NC = 512, NN = 4096, ND = 64;
static constexpr float LOG2E = 1.4426950408889634f;

__device__ __forceinline__ short f2bf(float f) {
  union { float f; unsigned u; } v; v.f = f;
  unsigned r = v.u + 0x7FFFu + ((v.u >> 16) & 1u);
  return (short)(r >> 16);
}

__device__ __forceinline__ unsigned cvt_pk_bf16(float a, float b) {
  unsigned r;
  asm("v_cvt_pk_bf16_f32 %0, %1, %2" : "=v"(r) : "v"(a), "v"(b));
  return r;
}

__device__ __forceinline__ void gld16(void* lds, const void* g) {
  __builtin_amdgcn_global_load_lds(
      (const __attribute__((address_space(1))) unsigned*)g,
      (__attribute__((address_space(3))) unsigned*)lds, 16, 0, 0);
}

// ---------------- kernel 1: cast weights to bf16 ----------------
__global__ void cast_w(const float* Wq, const float* Wk, const float* Wv,
                       short* Wqb, short* Wkb, short* Wvb) {
  int i = blockIdx.x * 256 + threadIdx.x;
  if (i < ND * NC) { Wqb[i] = f2bf(Wq[i]); Wkb[i] = f2bf(Wk[i]); }
  if (i < NC * NC) { Wvb[i] = f2bf(Wv[i]); }
}

// ---------------- kernel 2: x (B,C,N) f32 -> xT (B,N,C) bf16 (LDS-free) ------
__global__ __launch_bounds__(256) void transpose_x(const float* x, short* xT) {
  int b = blockIdx.z, c0 = blockIdx.y * 32, n0 = blockIdx.x * 64;
  int tid = threadIdx.x;
  int n = n0 + (tid >> 2);
  int c = c0 + (tid & 3) * 8;
  const float* xb = x + (size_t)b * NC * NN;
  bf16x8 v;
  #pragma unroll
  for (int i = 0; i < 8; i++) v[i] = f2bf(xb[(size_t)(c + i) * NN + n]);
  *(bf16x8*)(xT + ((size_t)b * NN + n) * NC + c) = v;
}

// ---------------- kernel 3: Q,K projections -> (B,N,64) bf16 ----------------
// Q pre-scaled by log2(e): downstream softmax uses exp2.
__global__ __launch_bounds__(256) void proj_qk(const short* xT, const short* Wqb, const short* Wkb,
                        const float* bq, const float* bk, short* Q, short* K) {
  int b = blockIdx.y;
  int wave = threadIdx.x >> 6, lane = threadIdx.x & 63;
  int lc = lane & 15, grp = lane >> 4;
  int n0 = blockIdx.x * 64 + wave * 16;
  const short* xTb = xT + ((size_t)b * NN + n0) * NC;
  f32x4 accq[4] = {}, acck[4] = {};
  for (int c0 = 0; c0 < NC; c0 += 32) {
    bf16x8 a = *(const bf16x8*)(xTb + (size_t)lc * NC + c0 + grp * 8);
    #pragma unroll
    for (int di = 0; di < 4; di++) {
      bf16x8 wq = *(const bf16x8*)(Wqb + (size_t)(di * 16 + lc) * NC + c0 + grp * 8);
      bf16x8 wk = *(const bf16x8*)(Wkb + (size_t)(di * 16 + lc) * NC + c0 + grp * 8);
      accq[di] = MFMA(a, wq, accq[di]);
      acck[di] = MFMA(a, wk, acck[di]);
    }
  }
  short* Qb = Q + (size_t)b * NN * ND;
  short* Kb = K + (size_t)b * NN * ND;
  #pragma unroll
  for (int di = 0; di < 4; di++)
    #pragma unroll
    for (int j = 0; j < 4; j++) {
      int n = n0 + grp * 4 + j;
      int d = di * 16 + lc;
      Qb[(size_t)n * ND + d] = f2bf((accq[di][j] + bq[d]) * LOG2E);
      Kb[(size_t)n * ND + d] = f2bf(acck[di][j] + bk[d]);
    }
}

// ---------------- kernel 4: V projection -> (B,C,N) bf16 (natural layout) ----
__global__ __launch_bounds__(256, 2) void proj_v(const short* xT, const short* Wvb,
                                                 const float* bv, short* V) {
  __shared__ char lds[65536];   // dbuf: [Wv 16K | xT 16K] x2
  int b = blockIdx.z;
  int tid = threadIdx.x, wv = tid >> 6, lane = tid & 63;
  int lc = lane & 15, grp = lane >> 4;
  int e0 = blockIdx.y * 128;
  int n0 = blockIdx.x * 128;
  const char* Wg = (const char*)Wvb;
  const char* Xg = (const char*)(xT + (size_t)b * NN * NC);
  int eq = (wv >> 1) * 64, nq = (wv & 1) * 64;

  auto stage = [&](int t) {
    char* buf = lds + (t & 1) * 32768;
    int c0 = t * 64;
    #pragma unroll
    for (int i = 0; i < 4; i++) {
      int r = wv * 32 + i * 8 + (lane >> 3), g = lane & 7;
      gld16(buf + wv * 4096 + i * 1024 + lane * 16,
            Wg + (size_t)(e0 + r) * 1024 + (size_t)c0 * 2 + ((g ^ (r & 7)) * 16));
    }
    #pragma unroll
    for (int i = 0; i < 4; i++) {
      int r = wv * 32 + i * 8 + (lane >> 3), g = lane & 7;
      gld16(buf + 16384 + wv * 4096 + i * 1024 + lane * 16,
            Xg + (size_t)(n0 + r) * 1024 + (size_t)c0 * 2 + ((g ^ (r & 7)) * 16));
    }
  };

  f32x4 acc[4][4] = {};
  stage(0);
  for (int t = 0; t < 8; t++) {
    asm volatile("s_waitcnt vmcnt(0)" ::: "memory");
    __builtin_amdgcn_sched_barrier(0);
    __builtin_amdgcn_s_barrier();
    if (t < 7) stage(t + 1);
    const char* buf = lds + (t & 1) * 32768;
    bf16x8 wf[4][2], xf[4][2];
    #pragma unroll
    for (int mi = 0; mi < 4; mi++)
      #pragma unroll
      for (int ks = 0; ks < 2; ks++) {
        int r = eq + mi * 16 + lc;
        wf[mi][ks] = *(const bf16x8*)(buf + r * 128 + (((ks * 4 + grp) ^ (r & 7)) * 16));
      }
    #pragma unroll
    for (int ni = 0; ni < 4; ni++)
      #pragma unroll
      for (int ks = 0; ks < 2; ks++) {
        int r = nq + ni * 16 + lc;
        xf[ni][ks] = *(const bf16x8*)(buf + 16384 + r * 128 + (((ks * 4 + grp) ^ (r & 7)) * 16));
      }
    #pragma unroll
    for (int mi = 0; mi < 4; mi++)
      #pragma unroll
      for (int ni = 0; ni < 4; ni++) {
        acc[mi][ni] = MFMA(wf[mi][0], xf[ni][0], acc[mi][ni]);
        acc[mi][ni] = MFMA(wf[mi][1], xf[ni][1], acc[mi][ni]);
      }
  }
  short* Vbp = V + (size_t)b * NC * NN;
  #pragma unroll
  for (int mi = 0; mi < 4; mi++)
    #pragma unroll
    for (int j = 0; j < 4; j++) {
      int e = e0 + eq + mi * 16 + grp * 4 + j;
      float bb = bv[e];
      #pragma unroll
      for (int ni = 0; ni < 4; ni++) {
        int n = n0 + nq + ni * 16 + lc;
        Vbp[(size_t)e * NN + n] = f2bf(acc[mi][ni][j] + bb);
      }
    }
}

// ---------------- kernel 5: softmax stats, 4-way n-split partials ----------------
__global__ __launch_bounds__(256, 2) void attn_stats(const short* Q, const short* K,
                                                     float* Mp, float* Lp) {
  __shared__ char lds[16384];
  int b = blockIdx.y, nh = blockIdx.z;
  int tid = threadIdx.x, wave = tid >> 6, lane = tid & 63;
  int lc = lane & 15, grp = lane >> 4;
  int m0 = blockIdx.x * 128 + wave * 32;
  const short* Qb = Q + (size_t)b * NN * ND;
  const char* Kg = (const char*)(K + (size_t)b * NN * ND);

  int kR[2], kC[2];
  #pragma unroll
  for (int i = 0; i < 2; i++) {
    int A = (wave * 2 + i) * 1024 + lane * 16;
    kR[i] = A >> 7;
    kC[i] = ((A >> 4) & 7) ^ (kR[i] & 7);
  }
  auto stageK = [&](char* base0, int n0) {
    #pragma unroll
    for (int i = 0; i < 2; i++)
      gld16(base0 + (wave * 2 + i) * 1024,
            Kg + (size_t)(n0 + kR[i]) * 128 + kC[i] * 16);
  };

  bf16x8 qf[2][2];
  #pragma unroll
  for (int mi = 0; mi < 2; mi++)
    #pragma unroll
    for (int kk = 0; kk < 2; kk++)
      qf[mi][kk] = *(const bf16x8*)(Qb + (size_t)(m0 + mi * 16 + lc) * ND + kk * 32 + grp * 8);

  float rmax[2][4], rsum[2][4];
  #pragma unroll
  for (int mi = 0; mi < 2; mi++)
    #pragma unroll
    for (int j = 0; j < 4; j++) { rmax[mi][j] = -1e30f; rsum[mi][j] = 0.f; }

  stageK(lds, nh * 1024);
  __syncthreads();
  int cur = 0;
  for (int tt = 0; tt < 16; tt++) {
    int t = nh * 16 + tt;
    if (tt + 1 < 16) stageK(lds + (cur ^ 1) * 8192, (t + 1) * 64);
    const char* Kb_l = lds + cur * 8192;
    f32x4 s[2][4] = {};
    #pragma unroll
    for (int ni = 0; ni < 4; ni++) {
      int row = ni * 16 + lc;
      bf16x8 kf0 = *(const bf16x8*)(Kb_l + row * 128 + ((grp ^ (row & 7)) * 16));
      bf16x8 kf1 = *(const bf16x8*)(Kb_l + row * 128 + (((grp + 4) ^ (row & 7)) * 16));
      #pragma unroll
      for (int mi = 0; mi < 2; mi++) {
        s[mi][ni] = MFMA(qf[mi][0], kf0, s[mi][ni]);
        s[mi][ni] = MFMA(qf[mi][1], kf1, s[mi][ni]);
      }
    }
    #pragma unroll
    for (int mi = 0; mi < 2; mi++)
      #pragma unroll
      for (int j = 0; j < 4; j++) {
        float a0 = s[mi][0][j], a1 = s[mi][1][j], a2 = s[mi][2][j], a3 = s[mi][3][j];
        float m4 = fmaxf(fmaxf(a0, a1), fmaxf(a2, a3));
        float nm = fmaxf(rmax[mi][j], m4);
        rsum[mi][j] = rsum[mi][j] * exp2f(rmax[mi][j] - nm)
                    + exp2f(a0 - nm) + exp2f(a1 - nm) + exp2f(a2 - nm) + exp2f(a3 - nm);
        rmax[mi][j] = nm;
      }
    __syncthreads();
    cur ^= 1;
  }
  #pragma unroll
  for (int mi = 0; mi < 2; mi++)
    #pragma unroll
    for (int j = 0; j < 4; j++) {
      float gm = rmax[mi][j];
      for (int o = 1; o < 16; o <<= 1) gm = fmaxf(gm, __shfl_xor(gm, o));
      float ps = rsum[mi][j] * exp2f(rmax[mi][j] - gm);
      for (int o = 1; o < 16; o <<= 1) ps += __shfl_xor(ps, o);
      if (lc == 0) {
        int m = m0 + mi * 16 + grp * 4 + j;
        Mp[((size_t)nh * NB + b) * NN + m] = gm;
        Lp[((size_t)nh * NB + b) * NN + m] = ps;
      }
    }
}

__global__ void stats_combine(const float* Mp, const float* Lp, float* Mrow, float* Lrow) {
  int i = blockIdx.x * 256 + threadIdx.x;
  if (i >= NB * NN) return;
  float M = Mp[i];
  #pragma unroll
  for (int s = 1; s < 4; s++) M = fmaxf(M, Mp[(size_t)s * NB * NN + i]);
  float L = 0.f;
  #pragma unroll
  for (int s = 0; s < 4; s++)
    L += Lp[(size_t)s * NB * NN + i] * exp2f(Mp[(size_t)s * NB * NN + i] - M);
  Mrow[i] = M; Lrow[i] = L;
}

// ---------------- kernel 6: out = gamma * (softmax(QK^T) @ V^T) + x ----------
// Block = 64m x 256e, 4 waves of 64m x 64e sharing the m-panel. Swapped QK^T
// split 4-ways over n (each wave does P[64m][16n] per step); P via 8K LDS tile.
// Softmax recompute factor 2 (e-halves). -M folded into MFMA C-init.
// LDS: K 8K (sb) | P 8K | V dbuf 2x32K = 80K -> 2 blocks/CU.
// Grid 512, bid&7 = (b, e-half) -> XCD-pinned 4MB V panel in L2.
__global__ __launch_bounds__(256, 2) void attn_out_kernel(
    const short* Q, const short* K, const short* V,
    const float* Mrow, const float* Lrow, const float* x,
    const float* gamma, float* out) {
  __shared__ char lds[81920];
  int bid = blockIdx.x;
  int combo = bid & 7;
  int b = combo >> 1;
  int e0 = (combo & 1) * 256;
  int m0 = (bid >> 3) * 64;
  int tid = threadIdx.x, we = tid >> 6, lane = tid & 63;
  int lc = lane & 15, grp = lane >> 4;

  char* Kl = lds;                // 64n x 64d (swizzled 128B rows)
  char* Pl = lds + 8192;         // 64m x 64n (swizzled 128B rows)
  char* Vb0 = lds + 16384;       // dbuf: 2 x (256e x 64n)

  const short* Qb = Q + (size_t)b * NN * ND;
  const char* Kg = (const char*)(K + (size_t)b * NN * ND);
  const char* Vg = (const char*)(V + (size_t)b * NC * NN);

  int kR[2], kC[2], vR[8], vC[8];
  #pragma unroll
  for (int i = 0; i < 2; i++) {
    int ch = i * 256 + tid;
    kR[i] = ch >> 3; kC[i] = (ch & 7) ^ (kR[i] & 7);
  }
  #pragma unroll
  for (int i = 0; i < 8; i++) {
    int ch = i * 256 + tid;
    vR[i] = ch >> 3; vC[i] = (ch & 7) ^ (vR[i] & 7);
  }
  auto stageK = [&](int n0) {
    #pragma unroll
    for (int i = 0; i < 2; i++)
      gld16(Kl + (i * 256 + tid) * 16, Kg + (size_t)(n0 + kR[i]) * 128 + kC[i] * 16);
  };
  auto stageV = [&](char* dst, int n0) {
    #pragma unroll
    for (int i = 0; i < 8; i++)
      gld16(dst + (i * 256 + tid) * 16,
            Vg + (size_t)(e0 + vR[i]) * 8192 + (size_t)n0 * 2 + vC[i] * 16);
  };

  bf16x8 qf[4][2];
  #pragma unroll
  for (int mi = 0; mi < 4; mi++)
    #pragma unroll
    for (int dk = 0; dk < 2; dk++)
      qf[mi][dk] = *(const bf16x8*)(Qb + (size_t)(m0 + mi * 16 + lc) * ND + dk * 32 + grp * 8);
  float Mr[4];
  #pragma unroll
  for (int mi = 0; mi < 4; mi++)
    Mr[mi] = Mrow[(size_t)b * NN + m0 + mi * 16 + lc];

  f32x4 acc[4][4] = {};   // [mi][ei]: 64m x 64e

  stageK(0);
  stageV(Vb0, 0);
  __syncthreads();
  for (int t = 0; t < 64; t++) {
    const char* Vl = Vb0 + (t & 1) * 32768;
    // ---- phase a: this wave's P slice: S^T[16n x 64m], n = we*16 + ...
    int krow = we * 16 + lc;
    bf16x8 kf0 = *(const bf16x8*)(Kl + krow * 128 + ((grp ^ (krow & 7)) * 16));
    bf16x8 kf1 = *(const bf16x8*)(Kl + krow * 128 + (((4 + grp) ^ (krow & 7)) * 16));
    #pragma unroll
    for (int mi = 0; mi < 4; mi++) {
      f32x4 s = {-Mr[mi], -Mr[mi], -Mr[mi], -Mr[mi]};
      s = MFMA(kf0, qf[mi][0], s);
      s = MFMA(kf1, qf[mi][1], s);
      unsigned w0 = cvt_pk_bf16(exp2f(s[0]), exp2f(s[1]));
      unsigned w1 = cvt_pk_bf16(exp2f(s[2]), exp2f(s[3]));
      int prow = mi * 16 + lc;
      char* base = Pl + prow * 128 + (((2 * we + (grp >> 1)) ^ (prow & 7)) << 4) + (grp & 1) * 8;
      *(unsigned*)base = w0;
      *(unsigned*)(base + 4) = w1;
    }
    __syncthreads();   // P(t) published; all kf reads done
    // ---- phase c: prefetch next tiles, then PV from P + V(t)
    if (t < 63) {
      stageK((t + 1) * 64);
      stageV(Vb0 + ((t + 1) & 1) * 32768, (t + 1) * 64);
    }
    bf16x8 pa[4][2];
    #pragma unroll
    for (int mi = 0; mi < 4; mi++)
      #pragma unroll
      for (int ks = 0; ks < 2; ks++) {
        int prow = mi * 16 + lc;
        pa[mi][ks] = *(const bf16x8*)(Pl + prow * 128 + (((ks * 4 + grp) ^ (prow & 7)) * 16));
      }
    #pragma unroll
    for (int ei = 0; ei < 4; ei++) {
      int vrow = we * 64 + ei * 16 + lc;
      bf16x8 v0 = *(const bf16x8*)(Vl + vrow * 128 + ((grp ^ (vrow & 7)) * 16));
      bf16x8 v1 = *(const bf16x8*)(Vl + vrow * 128 + (((4 + grp) ^ (vrow & 7)) * 16));
      #pragma unroll
      for (int mi = 0; mi < 4; mi++) {
        acc[mi][ei] = MFMA(pa[mi][0], v0, acc[mi][ei]);
        acc[mi][ei] = MFMA(pa[mi][1], v1, acc[mi][ei]);
      }
    }
    __syncthreads();   // drains stage vmcnt; P/V reads complete before reuse
  }

  // ---- epilogue: out[e][m] = gamma * acc / L + x
  float Li[4][4];
  #pragma unroll
  for (int mi = 0; mi < 4; mi++)
    #pragma unroll
    for (int j = 0; j < 4; j++)
      Li[mi][j] = 1.0f / Lrow[(size_t)b * NN + m0 + mi * 16 + grp * 4 + j];
  const float* xb = x + (size_t)b * NC * NN;
  float* ob = out + (size_t)b * NC * NN;
  float g = gamma[0];
  #pragma unroll
  for (int mi = 0; mi < 4; mi++)
    #pragma unroll
    for (int ei = 0; ei < 4; ei++) {
      int e = e0 + we * 64 + ei * 16 + lc;
      int mbase = m0 + mi * 16 + grp * 4;
      f32x4 xv = *(const f32x4*)(xb + (size_t)e * NN + mbase);
      f32x4 r;
      #pragma unroll
      for (int j = 0; j < 4; j++)
        r[j] = g * (acc[mi][ei][j] * Li[mi][j]) + xv[j];
      *(f32x4*)(ob + (size_t)e * NN + mbase) = r;
    }
}

extern "C" void kernel_launch(void* const* d_in, const int* in_sizes, int n_in,
                              void* d_out, int out_size, void* d_ws, size_t ws_size,
                              hipStream_t stream) {
  const float* x     = (const float*)d_in[0];
  const float* Wq    = (const float*)d_in[1];
  const float* bq    = (const float*)d_in[2];
  const float* Wk    = (const float*)d_in[3];
  const float* bk    = (const float*)d_in[4];
  const float* Wv    = (const float*)d_in[5];
  const float* bv    = (const float*)d_in[6];
  const float* gamma = (const float*)d_in[7];
  float* out = (float*)d_out;

  char* ws = (char*)d_ws;
  size_t off = 0;
  auto alloc = [&](size_t bytes) {
    void* p = ws + off;
    off = (off + bytes + 255) & ~(size_t)255;
    return p;
  };
  short* xT   = (short*)alloc((size_t)NB * NN * NC * 2);   // 16 MB
  short* Wqb  = (short*)alloc((size_t)ND * NC * 2);
  short* Wkb  = (short*)alloc((size_t)ND * NC * 2);
  short* Wvb  = (short*)alloc((size_t)NC * NC * 2);
  short* Qb   = (short*)alloc((size_t)NB * NN * ND * 2);   // 2 MB
  short* Kb   = (short*)alloc((size_t)NB * NN * ND * 2);   // 2 MB
  short* Vb   = (short*)alloc((size_t)NB * NC * NN * 2);   // 16 MB
  float* Mrow = (float*)alloc((size_t)NB * NN * 4);
  float* Lrow = (float*)alloc((size_t)NB * NN * 4);
  float* Mp   = (float*)alloc((size_t)4 * NB * NN * 4);
  float* Lp   = (float*)alloc((size_t)4 * NB * NN * 4);

  cast_w<<<dim3(1024), dim3(256), 0, stream>>>(Wq, Wk, Wv, Wqb, Wkb, Wvb);
  transpose_x<<<dim3(NN / 64, NC / 32, NB), dim3(256), 0, stream>>>(x, xT);
  proj_qk<<<dim3(NN / 64, NB), dim3(256), 0, stream>>>(xT, Wqb, Wkb, bq, bk, Qb, Kb);
  proj_v<<<dim3(NN / 128, NC / 128, NB), dim3(256), 0, stream>>>(xT, Wvb, bv, Vb);
  attn_stats<<<dim3(NN / 128, NB, 4), dim3(256), 0, stream>>>(Qb, Kb, Mp, Lp);
  stats_combine<<<dim3(NB * NN / 256), dim3(256), 0, stream>>>(Mp, Lp, Mrow, Lrow);
  attn_out_kernel<<<dim3(512), dim3(256), 0, stream>>>(
      Qb, Kb, Vb, Mrow, Lrow, x, gamma, out);
}